// Round 14
// baseline (396.243 us; speedup 1.0000x reference)
//
#include <hip/hip_runtime.h>
#include <hip/hip_bf16.h>

typedef unsigned short u16;
typedef short bf16x8 __attribute__((ext_vector_type(8)));
typedef float f32x4 __attribute__((ext_vector_type(4)));

#define T_DIM 2048
#define C_DIM 2048
#define F_DIM 8192
#define WKV_L 32
#define WKV_P (T_DIM / WKV_L)   // 64 chunks

// ---------- helpers ----------
__device__ __forceinline__ u16 f2bf(float f) {
    unsigned int u = __float_as_uint(f);
    u += 0x7fff + ((u >> 16) & 1);          // round-to-nearest-even
    return (u16)(u >> 16);
}

__device__ __forceinline__ void async16(const void* g, void* l) {
    __builtin_amdgcn_global_load_lds(
        (__attribute__((address_space(1))) const unsigned int*)g,
        (__attribute__((address_space(3))) unsigned int*)l, 16, 0, 0);
}

// ---------- fused LayerNorm + token-shift mix (3 outputs) ----------
__global__ __launch_bounds__(256) void ln_mix3(
        const float* __restrict__ x, const float* __restrict__ sh,
        const float* __restrict__ w, const float* __restrict__ b,
        const float* __restrict__ mk, const float* __restrict__ mv,
        const float* __restrict__ mr,
        u16* __restrict__ xk, u16* __restrict__ xv, u16* __restrict__ xr) {
    __shared__ float red[16];
    const int t = blockIdx.x, tid = threadIdx.x;
    const float4* cr = (const float4*)(x + (size_t)t * C_DIM);
    float4 c0 = cr[tid * 2], c1 = cr[tid * 2 + 1];
    float s = c0.x + c0.y + c0.z + c0.w + c1.x + c1.y + c1.z + c1.w;
    float q = c0.x * c0.x + c0.y * c0.y + c0.z * c0.z + c0.w * c0.w
            + c1.x * c1.x + c1.y * c1.y + c1.z * c1.z + c1.w * c1.w;
    float4 p0, p1;
    float sp = 0.f, qp = 0.f;
    if (t > 0) {
        const float4* pr = (const float4*)(x + (size_t)(t - 1) * C_DIM);
        p0 = pr[tid * 2]; p1 = pr[tid * 2 + 1];
        sp = p0.x + p0.y + p0.z + p0.w + p1.x + p1.y + p1.z + p1.w;
        qp = p0.x * p0.x + p0.y * p0.y + p0.z * p0.z + p0.w * p0.w
           + p1.x * p1.x + p1.y * p1.y + p1.z * p1.z + p1.w * p1.w;
    } else {
        const float4* pr = (const float4*)sh;
        p0 = pr[tid * 2]; p1 = pr[tid * 2 + 1];
    }
    #pragma unroll
    for (int off = 32; off > 0; off >>= 1) {
        s += __shfl_down(s, off);   q += __shfl_down(q, off);
        sp += __shfl_down(sp, off); qp += __shfl_down(qp, off);
    }
    const int lane = tid & 63, wv = tid >> 6;
    if (lane == 0) { red[wv] = s; red[4 + wv] = q; red[8 + wv] = sp; red[12 + wv] = qp; }
    __syncthreads();
    if (tid == 0) {
        red[0] += red[1] + red[2] + red[3];
        red[4] += red[5] + red[6] + red[7];
        red[8] += red[9] + red[10] + red[11];
        red[12] += red[13] + red[14] + red[15];
    }
    __syncthreads();
    const float mc = red[0] * (1.f / C_DIM);
    const float ic = rsqrtf(red[4] * (1.f / C_DIM) - mc * mc + 1e-5f);
    const float mp = red[8] * (1.f / C_DIM);
    const float ip = rsqrtf(red[12] * (1.f / C_DIM) - mp * mp + 1e-5f);
    const float4* w4 = (const float4*)w;
    const float4* b4 = (const float4*)b;
    #pragma unroll
    for (int j = 0; j < 2; ++j) {
        const int i4 = tid * 2 + j;
        float4 cv = j ? c1 : c0, pv = j ? p1 : p0;
        float4 wv4 = w4[i4], bv = b4[i4];
        float4 cl, pl;
        cl.x = (cv.x - mc) * ic * wv4.x + bv.x;
        cl.y = (cv.y - mc) * ic * wv4.y + bv.y;
        cl.z = (cv.z - mc) * ic * wv4.z + bv.z;
        cl.w = (cv.w - mc) * ic * wv4.w + bv.w;
        if (t > 0) {
            pl.x = (pv.x - mp) * ip * wv4.x + bv.x;
            pl.y = (pv.y - mp) * ip * wv4.y + bv.y;
            pl.z = (pv.z - mp) * ip * wv4.z + bv.z;
            pl.w = (pv.w - mp) * ip * wv4.w + bv.w;
        } else pl = pv;
        const size_t o = (size_t)t * (C_DIM / 4) + i4;
        float4 m;
        ushort4 r;
        m = ((const float4*)mk)[i4];
        r.x = f2bf(cl.x * m.x + pl.x * (1.f - m.x));
        r.y = f2bf(cl.y * m.y + pl.y * (1.f - m.y));
        r.z = f2bf(cl.z * m.z + pl.z * (1.f - m.z));
        r.w = f2bf(cl.w * m.w + pl.w * (1.f - m.w));
        ((ushort4*)xk)[o] = r;
        m = ((const float4*)mv)[i4];
        r.x = f2bf(cl.x * m.x + pl.x * (1.f - m.x));
        r.y = f2bf(cl.y * m.y + pl.y * (1.f - m.y));
        r.z = f2bf(cl.z * m.z + pl.z * (1.f - m.z));
        r.w = f2bf(cl.w * m.w + pl.w * (1.f - m.w));
        ((ushort4*)xv)[o] = r;
        m = ((const float4*)mr)[i4];
        r.x = f2bf(cl.x * m.x + pl.x * (1.f - m.x));
        r.y = f2bf(cl.y * m.y + pl.y * (1.f - m.y));
        r.z = f2bf(cl.z * m.z + pl.z * (1.f - m.z));
        r.w = f2bf(cl.w * m.w + pl.w * (1.f - m.w));
        ((ushort4*)xr)[o] = r;
    }
}

// ---------- fused LayerNorm + token-shift mix (2 outputs) ----------
__global__ __launch_bounds__(256) void ln_mix2(
        const float* __restrict__ x, const float* __restrict__ sh,
        const float* __restrict__ w, const float* __restrict__ b,
        const float* __restrict__ mk, const float* __restrict__ mr,
        u16* __restrict__ fk, u16* __restrict__ fr) {
    __shared__ float red[16];
    const int t = blockIdx.x, tid = threadIdx.x;
    const float4* cr = (const float4*)(x + (size_t)t * C_DIM);
    float4 c0 = cr[tid * 2], c1 = cr[tid * 2 + 1];
    float s = c0.x + c0.y + c0.z + c0.w + c1.x + c1.y + c1.z + c1.w;
    float q = c0.x * c0.x + c0.y * c0.y + c0.z * c0.z + c0.w * c0.w
            + c1.x * c1.x + c1.y * c1.y + c1.z * c1.z + c1.w * c1.w;
    float4 p0, p1;
    float sp = 0.f, qp = 0.f;
    if (t > 0) {
        const float4* pr = (const float4*)(x + (size_t)(t - 1) * C_DIM);
        p0 = pr[tid * 2]; p1 = pr[tid * 2 + 1];
        sp = p0.x + p0.y + p0.z + p0.w + p1.x + p1.y + p1.z + p1.w;
        qp = p0.x * p0.x + p0.y * p0.y + p0.z * p0.z + p0.w * p0.w
           + p1.x * p1.x + p1.y * p1.y + p1.z * p1.z + p1.w * p1.w;
    } else {
        const float4* pr = (const float4*)sh;
        p0 = pr[tid * 2]; p1 = pr[tid * 2 + 1];
    }
    #pragma unroll
    for (int off = 32; off > 0; off >>= 1) {
        s += __shfl_down(s, off);   q += __shfl_down(q, off);
        sp += __shfl_down(sp, off); qp += __shfl_down(qp, off);
    }
    const int lane = tid & 63, wv = tid >> 6;
    if (lane == 0) { red[wv] = s; red[4 + wv] = q; red[8 + wv] = sp; red[12 + wv] = qp; }
    __syncthreads();
    if (tid == 0) {
        red[0] += red[1] + red[2] + red[3];
        red[4] += red[5] + red[6] + red[7];
        red[8] += red[9] + red[10] + red[11];
        red[12] += red[13] + red[14] + red[15];
    }
    __syncthreads();
    const float mc = red[0] * (1.f / C_DIM);
    const float ic = rsqrtf(red[4] * (1.f / C_DIM) - mc * mc + 1e-5f);
    const float mp = red[8] * (1.f / C_DIM);
    const float ip = rsqrtf(red[12] * (1.f / C_DIM) - mp * mp + 1e-5f);
    const float4* w4 = (const float4*)w;
    const float4* b4 = (const float4*)b;
    #pragma unroll
    for (int j = 0; j < 2; ++j) {
        const int i4 = tid * 2 + j;
        float4 cv = j ? c1 : c0, pv = j ? p1 : p0;
        float4 wv4 = w4[i4], bv = b4[i4];
        float4 cl, pl;
        cl.x = (cv.x - mc) * ic * wv4.x + bv.x;
        cl.y = (cv.y - mc) * ic * wv4.y + bv.y;
        cl.z = (cv.z - mc) * ic * wv4.z + bv.z;
        cl.w = (cv.w - mc) * ic * wv4.w + bv.w;
        if (t > 0) {
            pl.x = (pv.x - mp) * ip * wv4.x + bv.x;
            pl.y = (pv.y - mp) * ip * wv4.y + bv.y;
            pl.z = (pv.z - mp) * ip * wv4.z + bv.z;
            pl.w = (pv.w - mp) * ip * wv4.w + bv.w;
        } else pl = pv;
        const size_t o = (size_t)t * (C_DIM / 4) + i4;
        float4 m;
        ushort4 r;
        m = ((const float4*)mk)[i4];
        r.x = f2bf(cl.x * m.x + pl.x * (1.f - m.x));
        r.y = f2bf(cl.y * m.y + pl.y * (1.f - m.y));
        r.z = f2bf(cl.z * m.z + pl.z * (1.f - m.z));
        r.w = f2bf(cl.w * m.w + pl.w * (1.f - m.w));
        ((ushort4*)fk)[o] = r;
        m = ((const float4*)mr)[i4];
        r.x = f2bf(cl.x * m.x + pl.x * (1.f - m.x));
        r.y = f2bf(cl.y * m.y + pl.y * (1.f - m.y));
        r.z = f2bf(cl.z * m.z + pl.z * (1.f - m.z));
        r.w = f2bf(cl.w * m.w + pl.w * (1.f - m.w));
        ((ushort4*)fr)[o] = r;
    }
}

// ---------- f32 -> bf16 conversion ----------
__global__ __launch_bounds__(256) void cvt_bf16(const float* __restrict__ in,
                                                u16* __restrict__ out, int n8) {
    int i = blockIdx.x * 256 + threadIdx.x;
    const int stride = gridDim.x * 256;
    for (; i < n8; i += stride) {
        const float4* p = (const float4*)(in + (size_t)i * 8);
        float4 a = p[0], b = p[1];
        ushort4 lo, hi;
        lo.x = f2bf(a.x); lo.y = f2bf(a.y); lo.z = f2bf(a.z); lo.w = f2bf(a.w);
        hi.x = f2bf(b.x); hi.y = f2bf(b.y); hi.z = f2bf(b.z); hi.w = f2bf(b.w);
        ((ushort4*)out)[i * 2] = lo;
        ((ushort4*)out)[i * 2 + 1] = hi;
    }
}

// four C*C weights in one launch (blockIdx.y selects the array)
__global__ __launch_bounds__(256) void cvt4_bf16(const float* __restrict__ i0,
                                                 const float* __restrict__ i1,
                                                 const float* __restrict__ i2,
                                                 const float* __restrict__ i3,
                                                 u16* __restrict__ out, int n8) {
    const int sel = blockIdx.y;
    const float* in = sel == 0 ? i0 : (sel == 1 ? i1 : (sel == 2 ? i2 : i3));
    u16* o = out + (size_t)sel * n8 * 8;
    int i = blockIdx.x * 256 + threadIdx.x;
    const int stride = gridDim.x * 256;
    for (; i < n8; i += stride) {
        const float4* p = (const float4*)(in + (size_t)i * 8);
        float4 a = p[0], b = p[1];
        ushort4 lo, hi;
        lo.x = f2bf(a.x); lo.y = f2bf(a.y); lo.z = f2bf(a.z); lo.w = f2bf(a.w);
        hi.x = f2bf(b.x); hi.y = f2bf(b.y); hi.z = f2bf(b.z); hi.w = f2bf(b.w);
        ((ushort4*)o)[i * 2] = lo;
        ((ushort4*)o)[i * 2 + 1] = hi;
    }
}

// ---------- 4-way partial-sum reduce (float4) ----------
__global__ __launch_bounds__(256) void reduce4(const float* __restrict__ p0,
                                               const float* __restrict__ p1,
                                               const float* __restrict__ p2,
                                               const float* __restrict__ p3,
                                               float* __restrict__ o, int n4) {
    int i = blockIdx.x * 256 + threadIdx.x;
    const int stride = gridDim.x * 256;
    for (; i < n4; i += stride) {
        float4 a = ((const float4*)p0)[i], b = ((const float4*)p1)[i];
        float4 c = ((const float4*)p2)[i], d = ((const float4*)p3)[i];
        float4 r;
        r.x = a.x + b.x + c.x + d.x;
        r.y = a.y + b.y + c.y + d.y;
        r.z = a.z + b.z + c.z + d.z;
        r.w = a.w + b.w + c.w + d.w;
        ((float4*)o)[i] = r;
    }
}

// ---------- split-K combine kernels (proven R7) ----------
__global__ __launch_bounds__(256) void comb_add(const float* __restrict__ p0,
                                                const float* __restrict__ p1,
                                                const float* __restrict__ xin,
                                                float* __restrict__ o, int n4) {
    int i = blockIdx.x * 256 + threadIdx.x;
    const int stride = gridDim.x * 256;
    for (; i < n4; i += stride) {
        float4 a = ((const float4*)p0)[i], b = ((const float4*)p1)[i];
        float4 c = ((const float4*)xin)[i];
        float4 r;
        r.x = a.x + b.x + c.x;
        r.y = a.y + b.y + c.y;
        r.z = a.z + b.z + c.z;
        r.w = a.w + b.w + c.w;
        ((float4*)o)[i] = r;
    }
}

__global__ __launch_bounds__(256) void comb_sig(const float* __restrict__ p0,
                                                const float* __restrict__ p1,
                                                const float* __restrict__ x1,
                                                const float* __restrict__ kv,
                                                float* __restrict__ o, int n4) {
    int i = blockIdx.x * 256 + threadIdx.x;
    const int stride = gridDim.x * 256;
    for (; i < n4; i += stride) {
        float4 a = ((const float4*)p0)[i], b = ((const float4*)p1)[i];
        float4 c = ((const float4*)x1)[i], d = ((const float4*)kv)[i];
        float4 r;
        r.x = c.x + d.x / (1.f + expf(-(a.x + b.x)));
        r.y = c.y + d.y / (1.f + expf(-(a.y + b.y)));
        r.z = c.z + d.z / (1.f + expf(-(a.z + b.z)));
        r.w = c.w + d.w / (1.f + expf(-(a.w + b.w)));
        ((float4*)o)[i] = r;
    }
}

// ---------- WKV parallel scan ----------
__global__ __launch_bounds__(256) void wkv_part(const float* __restrict__ td,
                                                const float* __restrict__ k,
                                                const float* __restrict__ v,
                                                float* __restrict__ Ab,
                                                float* __restrict__ Bb) {
    const int idx = blockIdx.x * 256 + threadIdx.x;     // C*P threads
    const int c = idx & (C_DIM - 1);
    const int p = idx >> 11;
    const float ew = expf(-expf(td[c]));
    float A = 0.f, B = 0.f;
    size_t o = (size_t)(p * WKV_L) * C_DIM + c;
    #pragma unroll 4
    for (int i = 0; i < WKV_L; ++i, o += C_DIM) {
        const float kk = expf(k[o]);
        A = (A + kk * v[o]) * ew;
        B = (B + kk) * ew;
    }
    Ab[p * C_DIM + c] = A;
    Bb[p * C_DIM + c] = B;
}

__global__ __launch_bounds__(256) void wkv_comb(const float* __restrict__ td,
                                                const float* __restrict__ st,
                                                const float* __restrict__ Ab,
                                                const float* __restrict__ Bb,
                                                float* __restrict__ Sa,
                                                float* __restrict__ Sb) {
    const int c = blockIdx.x * 256 + threadIdx.x;       // C threads
    const float w = -expf(td[c]);
    const float dL = expf(w * (float)WKV_L);            // ew^L
    float a = st[c];
    float b = st[C_DIM + c];
    #pragma unroll 4
    for (int p = 0; p < WKV_P; ++p) {
        Sa[p * C_DIM + c] = a;
        Sb[p * C_DIM + c] = b;
        a = dL * a + Ab[p * C_DIM + c];
        b = dL * b + Bb[p * C_DIM + c];
    }
}

__global__ __launch_bounds__(256) void wkv_emit(const float* __restrict__ td,
                                                const float* __restrict__ tf,
                                                const float* __restrict__ k,
                                                const float* __restrict__ v,
                                                const float* __restrict__ r,
                                                const float* __restrict__ Sa,
                                                const float* __restrict__ Sb,
                                                u16* __restrict__ pout) {
    const int idx = blockIdx.x * 256 + threadIdx.x;     // C*P threads
    const int c = idx & (C_DIM - 1);
    const int p = idx >> 11;
    const float u = tf[c];
    const float w = -expf(td[c]);
    const float ew = expf(w);
    float a = Sa[p * C_DIM + c];
    float b = Sb[p * C_DIM + c];
    size_t o = (size_t)(p * WKV_L) * C_DIM + c;
    #pragma unroll 2
    for (int i = 0; i < WKV_L; ++i, o += C_DIM) {
        const float kt = k[o], vt = v[o], rt = r[o];
        const float e = expf(u + w + kt);
        const float y = (a + e * vt) / (b + e);
        const float kk = expf(kt);
        a = (a + kk * vt) * ew;
        b = (b + kk) * ew;
        const float sr = 1.f / (1.f + expf(-rt));
        pout[o] = f2bf(sr * y);
    }
}

enum { EPI_F32 = 0, EPI_ADDX = 1, EPI_RELU2 = 2, EPI_SIGMULADD = 3 };

// ---------- 128x128 bf16 NT GEMM — 3-slot pipeline (R9, proven) ----------
template <int EPI>
__global__ __launch_bounds__(256, 3) void gemm_bt(
        const u16* __restrict__ A, int lda, long a_zs,
        const u16* __restrict__ B, int ldb, long b_zs,
        long koff, int Kloop,
        void* __restrict__ outp, int ldo, long o_zs,
        const float* __restrict__ aux1, const float* __restrict__ aux2) {
    __shared__ u16 lds[3 * 8192];   // 48 KiB: 3 slots x (A 8KB + B 8KB)
    const int tid = threadIdx.x;
    const int l = tid & 63, w = tid >> 6;
    const int wr2 = w >> 1, wc2 = w & 1;     // 2x2 waves of 64x64

    const int gx = gridDim.x, gy = gridDim.y;
    const int nxy = gx * gy;
    const int flat = (blockIdx.z * gy + blockIdx.y) * gx + blockIdx.x;
    const int cpx = (nxy * gridDim.z) >> 3;
    const int swz = (flat & 7) * cpx + (flat >> 3);
    const int z = swz / nxy;
    const int rem = swz - z * nxy;
    const int bm = rem % gy;
    const int bn = rem / gy;

    const u16* Ag = A + (size_t)z * a_zs + (size_t)z * koff + (size_t)bm * 128 * lda;
    const u16* Bg = B + (size_t)z * b_zs + (size_t)z * koff + (size_t)bn * 128 * ldb;

    long gA[2], gB[2];
    int dA[2], dB[2];
    #pragma unroll
    for (int j = 0; j < 2; ++j) {
        const int off = j * 4096 + w * 1024 + l * 16;
        const int row = off >> 6;
        const int cb = (off & 63) ^ (((off >> 9) & 1) << 5);
        gA[j] = (long)row * lda + (cb >> 1);
        gB[j] = (long)row * ldb + (cb >> 1);
        dA[j] = j * 2048 + w * 512;
        dB[j] = 4096 + j * 2048 + w * 512;
    }

    int offA[4], offB[4];
    #pragma unroll
    for (int m = 0; m < 4; ++m) {
        const int lin = (wr2 * 64 + m * 16 + (l & 15)) * 64 + ((l >> 4) << 4);
        offA[m] = (lin ^ (((lin >> 9) & 1) << 5)) >> 1;
    }
    #pragma unroll
    for (int n = 0; n < 4; ++n) {
        const int lin = (wc2 * 64 + n * 16 + (l & 15)) * 64 + ((l >> 4) << 4);
        offB[n] = 4096 + ((lin ^ (((lin >> 9) & 1) << 5)) >> 1);
    }

    const f32x4 fz = {0.f, 0.f, 0.f, 0.f};
    f32x4 acc[4][4];
    #pragma unroll
    for (int m = 0; m < 4; ++m)
        #pragma unroll
        for (int n = 0; n < 4; ++n) acc[m][n] = fz;

    const int NT = Kloop >> 5;

    auto stage = [&](int kt, int sp) {
        const long ko = (long)kt << 5;
        const int sb = sp * 8192;
        async16(Ag + gA[0] + ko, &lds[sb + dA[0]]);
        async16(Ag + gA[1] + ko, &lds[sb + dA[1]]);
        async16(Bg + gB[0] + ko, &lds[sb + dB[0]]);
        async16(Bg + gB[1] + ko, &lds[sb + dB[1]]);
    };

    stage(0, 0);
    stage(1, 1);

    int sr = 0;
    for (int t = 0; t < NT; ++t) {
        asm volatile("s_waitcnt vmcnt(4)" ::: "memory");
        __builtin_amdgcn_s_barrier();
        __builtin_amdgcn_sched_barrier(0);
        {
            const int tp = (t + 2 < NT) ? t + 2 : NT - 1;
            const int sp = (sr == 0) ? 2 : sr - 1;
            stage(tp, sp);
        }
        const int sb = sr * 8192;
        bf16x8 af[4], bfv[4];
        #pragma unroll
        for (int m = 0; m < 4; ++m) af[m] = *(const bf16x8*)&lds[sb + offA[m]];
        #pragma unroll
        for (int n = 0; n < 4; ++n) bfv[n] = *(const bf16x8*)&lds[sb + offB[n]];
        __builtin_amdgcn_s_setprio(1);
        #pragma unroll
        for (int m = 0; m < 2; ++m)
            #pragma unroll
            for (int n = 0; n < 4; ++n)
                acc[m][n] = __builtin_amdgcn_mfma_f32_16x16x32_bf16(af[m], bfv[n], acc[m][n], 0, 0, 0);
        __builtin_amdgcn_s_setprio(0);
        __builtin_amdgcn_s_setprio(1);
        #pragma unroll
        for (int m = 2; m < 4; ++m)
            #pragma unroll
            for (int n = 0; n < 4; ++n)
                acc[m][n] = __builtin_amdgcn_mfma_f32_16x16x32_bf16(af[m], bfv[n], acc[m][n], 0, 0, 0);
        __builtin_amdgcn_s_setprio(0);
        sr = (sr == 2) ? 0 : sr + 1;
    }
    asm volatile("s_waitcnt vmcnt(0)" ::: "memory");

    const int r00 = bm * 128 + wr2 * 64 + ((l >> 4) << 2);
    const int c00 = bn * 128 + wc2 * 64 + (l & 15);
    #pragma unroll
    for (int m = 0; m < 4; ++m) {
        #pragma unroll
        for (int n = 0; n < 4; ++n) {
            #pragma unroll
            for (int j = 0; j < 4; ++j) {
                const int rr = r00 + m * 16 + j;
                const int cc = c00 + n * 16;
                const size_t o = (size_t)rr * ldo + cc;
                const float val = acc[m][n][j];
                if constexpr (EPI == EPI_F32) {
                    ((float*)outp)[(size_t)z * o_zs + o] = val;
                } else if constexpr (EPI == EPI_ADDX) {
                    ((float*)outp)[o] = aux1[o] + val;
                } else if constexpr (EPI == EPI_RELU2) {
                    const float tp2 = fmaxf(val, 0.f);
                    ((u16*)outp)[o] = f2bf(tp2 * tp2);
                } else {  // EPI_SIGMULADD
                    const float sg = 1.f / (1.f + expf(-val));
                    ((float*)outp)[o] = aux1[o] + sg * aux2[o];
                }
            }
        }
    }
}

// ---------- 256x256 bf16 NT GEMM — 4-buffer deep-prefetch pipeline ---------
// R14: gemm3s (R13, verified pass) with prefetch depth 3 instead of 1.
// 4 bufs x 32KB = 128 KiB. Stage distance 3: tile kt stages A(kt+3) at ph0,
// B(kt+3) at ph1. Checkpoint vmcnt(6) at ph0-end (m201's constant):
//   stage-pair issue order: ..., A(kt+1)@kt-2ph0, B(kt+1)@kt-2ph1,
//   A(kt+2)@kt-1ph0, B(kt+2)@kt-1ph1, A(kt+3)@kt ph0.
//   vmcnt(6) leaves newest 6 loads {A(kt+3),B(kt+2),A(kt+2)} outstanding =>
//   tile kt+1 fully landed before ph1 reads it (then barrier). Loads get
//   ~5 phases (~1000cy) to land, covering HBM latency (~900cy) - this is the
//   depth gemm3s's vmcnt(2) lacked (forced landing in ~2 phases -> stall).
// Overwrite: ph0 stages into buf (kt+3)%4 = (kt-1)%4; tile kt-1's last
//   readers completed at its counted lgkm waits before its closing barriers,
//   all before this stage issues. lgkm ledger identical to R13 gemm3s.
// Prologue: tiles 0,1,2 staged (12 loads); vmcnt(8) => tile 0 landed;
//   pre-loop reads tile 0; first in-loop checkpoint reduces to steady state.
template <int EPI>
__global__ __launch_bounds__(512, 2) void gemm4s(
        const u16* __restrict__ A, int lda,
        const u16* __restrict__ B, int ldb,
        long koff, int Kloop,
        void* __restrict__ outp, int ldo, long o_zs) {
    __shared__ u16 lds[4 * 16384];   // 128 KiB
    const int tid = threadIdx.x;
    const int l = tid & 63, w = tid >> 6;
    const int wm = w >> 2, wn = w & 3;

    const int gx = gridDim.x, gy = gridDim.y;
    const int nxy = gx * gy;
    const int flat = (blockIdx.z * gy + blockIdx.y) * gx + blockIdx.x;
    const int cpx = (nxy * gridDim.z) >> 3;
    const int swzb = (flat & 7) * cpx + (flat >> 3);
    const int z = swzb / nxy;
    const int rem = swzb - z * nxy;
    const int bm = rem % gy;
    const int bn = rem / gy;

    const u16* Ag = A + (size_t)z * koff + (size_t)bm * 256 * lda;
    const u16* Bg = B + (size_t)z * koff + (size_t)bn * 256 * ldb;

    // staging: 2 halves per region; pre-swizzled global source, linear dest
    long srcA[2], srcB[2];
    int dstA[2], dstB[2];
    #pragma unroll
    for (int h = 0; h < 2; ++h) {
        const int off = h * 8192 + w * 1024 + l * 16;   // byte in 16KB region
        const int row = off >> 6;                        // 64B rows
        const int cbyte = (off & 63) ^ (((off >> 9) & 1) << 5);
        srcA[h] = (long)row * lda + (cbyte >> 1);
        srcB[h] = (long)row * ldb + (cbyte >> 1);
        dstA[h] = off >> 1;
        dstB[h] = 8192 + (off >> 1);
    }

    // ds_read fragment offsets (elem within buffer)
    int offAL[4], offAH[4], offB[4];
    #pragma unroll
    for (int mi = 0; mi < 4; ++mi) {
        int row = wm * 128 + mi * 16 + (l & 15);
        int lin = row * 64 + ((l >> 4) << 4);
        offAL[mi] = (lin ^ (((lin >> 9) & 1) << 5)) >> 1;
        lin = (row + 64) * 64 + ((l >> 4) << 4);
        offAH[mi] = (lin ^ (((lin >> 9) & 1) << 5)) >> 1;
    }
    #pragma unroll
    for (int n = 0; n < 4; ++n) {
        const int row = wn * 64 + n * 16 + (l & 15);
        const int lin = row * 64 + ((l >> 4) << 4);
        offB[n] = 8192 + ((lin ^ (((lin >> 9) & 1) << 5)) >> 1);
    }

    const f32x4 fz = {0.f, 0.f, 0.f, 0.f};
    f32x4 acc[8][4];
    #pragma unroll
    for (int m = 0; m < 8; ++m)
        #pragma unroll
        for (int n = 0; n < 4; ++n) acc[m][n] = fz;

    const int NT = Kloop >> 5;          // K-tiles of 32 (>=4, even at all sites)

    auto stgA = [&](int kt, int buf, int h) {
        async16(Ag + srcA[h] + (long)kt * 32, &lds[buf * 16384 + dstA[h]]);
    };
    auto stgB = [&](int kt, int buf, int h) {
        async16(Bg + srcB[h] + (long)kt * 32, &lds[buf * 16384 + dstB[h]]);
    };

    // prologue: tiles 0,1,2 staged (12 loads); vmcnt(8) -> tile 0 landed
    stgA(0, 0, 0); stgA(0, 0, 1); stgB(0, 0, 0); stgB(0, 0, 1);
    stgA(1, 1, 0); stgA(1, 1, 1); stgB(1, 1, 0); stgB(1, 1, 1);
    stgA(2, 2, 0); stgA(2, 2, 1); stgB(2, 2, 0); stgB(2, 2, 1);
    asm volatile("s_waitcnt vmcnt(8)" ::: "memory");
    __builtin_amdgcn_s_barrier();

    bf16x8 aX[4], bX[4], aY[4], bY[4];
    #pragma unroll
    for (int mi = 0; mi < 4; ++mi) aX[mi] = *(const bf16x8*)&lds[offAL[mi]];
    #pragma unroll
    for (int n = 0; n < 4; ++n) bX[n] = *(const bf16x8*)&lds[offB[n]];

    auto tile = [&](int kt, bf16x8 (&aC)[4], bf16x8 (&bbC)[4],
                    bf16x8 (&aN)[4], bf16x8 (&bbN)[4]) {
        const int cb = (kt & 3) * 16384;
        const int nb = ((kt + 1) & 3) * 16384;
        const int tb = (kt + 3) & 3;
        const int ksrc = (kt + 3 < NT) ? kt + 3 : NT - 1;
        bf16x8 aH[4];
        // ---- ph0: read m4-7 (cur buf) | stage A halves of kt+3 ----
        #pragma unroll
        for (int mi = 0; mi < 4; ++mi) aH[mi] = *(const bf16x8*)&lds[cb + offAH[mi]];
        stgA(ksrc, tb, 0); stgA(ksrc, tb, 1);
        __builtin_amdgcn_s_barrier();
        asm volatile("s_waitcnt lgkmcnt(4)" ::: "memory");   // prev-phase reads done
        __builtin_amdgcn_sched_barrier(0);
        __builtin_amdgcn_s_setprio(1);
        #pragma unroll
        for (int mi = 0; mi < 4; ++mi)
            #pragma unroll
            for (int n = 0; n < 4; ++n)
                acc[mi][n] = __builtin_amdgcn_mfma_f32_16x16x32_bf16(aC[mi], bbC[n], acc[mi][n], 0, 0, 0);
        __builtin_amdgcn_s_setprio(0);
        // deep-prefetch checkpoint: newest 6 loads {A(kt+3),B(kt+2),A(kt+2)}
        // may remain; tile kt+1 fully landed. Barrier orders cross-wave.
        asm volatile("s_waitcnt vmcnt(6)" ::: "memory");
        __builtin_amdgcn_s_barrier();
        // ---- ph1: read next tile m0-3+B (next buf) | stage B halves of kt+3 --
        #pragma unroll
        for (int mi = 0; mi < 4; ++mi) aN[mi] = *(const bf16x8*)&lds[nb + offAL[mi]];
        #pragma unroll
        for (int n = 0; n < 4; ++n) bbN[n] = *(const bf16x8*)&lds[nb + offB[n]];
        stgB(ksrc, tb, 0); stgB(ksrc, tb, 1);
        __builtin_amdgcn_s_barrier();
        asm volatile("s_waitcnt lgkmcnt(8)" ::: "memory");   // ph0's aH done
        __builtin_amdgcn_sched_barrier(0);
        __builtin_amdgcn_s_setprio(1);
        #pragma unroll
        for (int mi = 0; mi < 4; ++mi)
            #pragma unroll
            for (int n = 0; n < 4; ++n)
                acc[4 + mi][n] = __builtin_amdgcn_mfma_f32_16x16x32_bf16(aH[mi], bbC[n], acc[4 + mi][n], 0, 0, 0);
        __builtin_amdgcn_s_setprio(0);
        __builtin_amdgcn_s_barrier();
    };

    for (int kt = 0; kt < NT; kt += 2) {
        tile(kt, aX, bX, aY, bY);
        tile(kt + 1, aY, bY, aX, bX);
    }
    asm volatile("s_waitcnt vmcnt(0)" ::: "memory");  // drain tail stages

    // --- epilogue (verified 256²/8-wave mapping) ---
    const int r00 = bm * 256 + wm * 128 + ((l >> 4) << 2);
    const int c00 = bn * 256 + wn * 64 + (l & 15);
    #pragma unroll
    for (int m = 0; m < 8; ++m) {
        #pragma unroll
        for (int n = 0; n < 4; ++n) {
            #pragma unroll
            for (int j = 0; j < 4; ++j) {
                const int rr = r00 + m * 16 + j;
                const int cc = c00 + n * 16;
                const size_t o = (size_t)rr * ldo + cc;
                const float val = acc[m][n][j];
                if constexpr (EPI == EPI_F32) {
                    ((float*)outp)[(size_t)z * o_zs + o] = val;
                } else {  // EPI_RELU2
                    const float tp2 = fmaxf(val, 0.f);
                    ((u16*)outp)[o] = f2bf(tp2 * tp2);
                }
            }
        }
    }
}

// ---------- launcher ----------
extern "C" void kernel_launch(void* const* d_in, const int* in_sizes, int n_in,
                              void* d_out, int out_size, void* d_ws, size_t ws_size,
                              hipStream_t stream) {
    const float* x         = (const float*)d_in[0];
    const float* att_shift = (const float*)d_in[1];
    const float* wkv_state = (const float*)d_in[2];
    const float* ffn_shift = (const float*)d_in[3];
    const float* ln1w = (const float*)d_in[4];
    const float* ln1b = (const float*)d_in[5];
    const float* ln2w = (const float*)d_in[6];
    const float* ln2b = (const float*)d_in[7];
    const float* tmk  = (const float*)d_in[8];
    const float* tmv  = (const float*)d_in[9];
    const float* tmr  = (const float*)d_in[10];
    const float* td   = (const float*)d_in[11];
    const float* tf   = (const float*)d_in[12];
    const float* Wk   = (const float*)d_in[13];
    const float* Wv   = (const float*)d_in[14];
    const float* Wr   = (const float*)d_in[15];
    const float* Wo   = (const float*)d_in[16];
    const float* ftmk = (const float*)d_in[17];
    const float* ftmr = (const float*)d_in[18];
    const float* Wfk  = (const float*)d_in[19];   // [F, C]
    const float* Wfv  = (const float*)d_in[20];   // [C, F]
    const float* Wfr  = (const float*)d_in[21];   // [C, C]
    float* out = (float*)d_out;

    char* ws = (char*)d_ws;
    const size_t MB = 1ull << 20;
    float* rx0 = (float*)(ws + 0);            // 16 MB f32 (reduced kv)
    u16*   xk  = (u16*)(ws + 16 * MB);        // 8 MB bf16       (also fk)
    u16*   xv  = (u16*)(ws + 24 * MB);        // 8 MB bf16       (also fr)
    u16*   xr  = (u16*)(ws + 32 * MB);        // 8 MB bf16
    float* kb  = (float*)(ws + 40 * MB);      // 16 MB f32
    float* vb  = (float*)(ws + 56 * MB);      // 16 MB f32
    float* rb  = (float*)(ws + 72 * MB);      // 16 MB f32
    u16*   pb  = (u16*)(ws + 88 * MB);        // 8 MB bf16
    float* x1  = (float*)(ws + 96 * MB);      // 16 MB f32
    u16*   kf  = (u16*)(ws + 112 * MB);       // 32 MB bf16 [T,F]
    u16*   Wb  = (u16*)(ws + 144 * MB);       // 32 MB bf16 weight scratch
    // wkv scratch overlays kf region (dead during TimeMix):
    float* wAb = (float*)(ws + 112 * MB);
    float* wBb = (float*)(ws + 112 * MB + 512 * 1024);
    float* wSa = (float*)(ws + 113 * MB);
    float* wSb = (float*)(ws + 113 * MB + 512 * 1024);
    // att_out split-K partials: kb/vb regions (dead after wkv_emit)
    float* aop = (float*)(ws + 40 * MB);      // 2 x 16 MB at 40,56
    // ffn_value split-K partials: 4 x 16 MB in [32,96) (xr/kb/vb/rb/pb dead)
    float* fvp = (float*)(ws + 32 * MB);
    // ffn_recept split-K partials: 2 x 16 MB at 40,56 (fvp consumed by then)
    float* rcp = (float*)(ws + 40 * MB);

    const int T = T_DIM, C = C_DIM, F = F_DIM;
    const dim3 blk(256), blk5(512);

    // --- TimeMix ---
    ln_mix3<<<T, blk, 0, stream>>>(x, att_shift, ln1w, ln1b, tmk, tmv, tmr, xk, xv, xr);

    // all four CxC weights in one launch: Wb = [Wk|Wv|Wr|Wo]
    cvt4_bf16<<<dim3(1024, 4), blk, 0, stream>>>(Wk, Wv, Wr, Wo, Wb, C * C / 8);
    // batched qkv: grid 16x16x3 = 768 blocks (128² kernel)
    gemm_bt<EPI_F32><<<dim3(C / 128, T / 128, 3), blk, 0, stream>>>(
        xk, C, (long)T * C, Wb, C, (long)C * C, 0, C,
        kb, C, (long)T * C, nullptr, nullptr);

    wkv_part<<<(C * WKV_P) / 256, blk, 0, stream>>>(td, kb, vb, wAb, wBb);
    wkv_comb<<<C / 256, blk, 0, stream>>>(td, wkv_state, wAb, wBb, wSa, wSb);
    wkv_emit<<<(C * WKV_P) / 256, blk, 0, stream>>>(td, tf, kb, vb, rb, wSa, wSb, pb);

    // att_out split-K x2: 512 blocks (2/CU), partials -> aop; then combine +x
    gemm_bt<EPI_F32><<<dim3(C / 128, T / 128, 2), blk, 0, stream>>>(
        pb, C, 0, Wb + 3 * (size_t)C * C, C, 0, 1024, 1024,
        aop, C, (long)T * C, nullptr, nullptr);
    comb_add<<<2048, blk, 0, stream>>>(aop, aop + (size_t)T * C, x, x1, T * C / 4);

    // --- ChannelMix ---
    ln_mix2<<<T, blk, 0, stream>>>(x1, ffn_shift, ln2w, ln2b, ftmk, ftmr, xk, xv);

    cvt_bf16<<<2048, blk, 0, stream>>>(Wfk, Wb, F * C / 8);
    // ffn_key on 256² deep-prefetch kernel: grid 32x8 = 256 blocks
    gemm4s<EPI_RELU2><<<dim3(F / 256, T / 256, 1), blk5, 0, stream>>>(
        xk, C, Wb, C, 0, C, kf, F, 0);

    cvt_bf16<<<2048, blk, 0, stream>>>(Wfv, Wb, C * F / 8);
    // ffn_value on 256², split-K x4 (koff=2048): 256 blocks
    gemm4s<EPI_F32><<<dim3(C / 256, T / 256, 4), blk5, 0, stream>>>(
        kf, F, Wb, F, 2048, 2048, fvp, C, (long)T * C);
    reduce4<<<2048, blk, 0, stream>>>(fvp, fvp + (size_t)T * C, fvp + 2 * (size_t)T * C,
                                      fvp + 3 * (size_t)T * C, rx0, T * C / 4);

    cvt_bf16<<<2048, blk, 0, stream>>>(Wfr, Wb, C * C / 8);
    // ffn_recept split-K x2: 512 blocks, partials -> rcp; fused combine
    gemm_bt<EPI_F32><<<dim3(C / 128, T / 128, 2), blk, 0, stream>>>(
        xv, C, 0, Wb, C, 0, 1024, 1024, rcp, C, (long)T * C, nullptr, nullptr);
    comb_sig<<<2048, blk, 0, stream>>>(rcp, rcp + (size_t)T * C, x1, rx0, out, T * C / 4);
}

// Round 15
// 381.551 us; speedup vs baseline: 1.0385x; 1.0385x over previous
//
#include <hip/hip_runtime.h>
#include <hip/hip_bf16.h>

typedef unsigned short u16;
typedef short bf16x8 __attribute__((ext_vector_type(8)));
typedef float f32x4 __attribute__((ext_vector_type(4)));

#define T_DIM 2048
#define C_DIM 2048
#define F_DIM 8192
#define WKV_L 32
#define WKV_P (T_DIM / WKV_L)   // 64 chunks

// ---------- helpers ----------
__device__ __forceinline__ u16 f2bf(float f) {
    unsigned int u = __float_as_uint(f);
    u += 0x7fff + ((u >> 16) & 1);          // round-to-nearest-even
    return (u16)(u >> 16);
}

__device__ __forceinline__ void async16(const void* g, void* l) {
    __builtin_amdgcn_global_load_lds(
        (__attribute__((address_space(1))) const unsigned int*)g,
        (__attribute__((address_space(3))) unsigned int*)l, 16, 0, 0);
}

// ---------- fused LayerNorm + token-shift mix (3 outputs) ----------
__global__ __launch_bounds__(256) void ln_mix3(
        const float* __restrict__ x, const float* __restrict__ sh,
        const float* __restrict__ w, const float* __restrict__ b,
        const float* __restrict__ mk, const float* __restrict__ mv,
        const float* __restrict__ mr,
        u16* __restrict__ xk, u16* __restrict__ xv, u16* __restrict__ xr) {
    __shared__ float red[16];
    const int t = blockIdx.x, tid = threadIdx.x;
    const float4* cr = (const float4*)(x + (size_t)t * C_DIM);
    float4 c0 = cr[tid * 2], c1 = cr[tid * 2 + 1];
    float s = c0.x + c0.y + c0.z + c0.w + c1.x + c1.y + c1.z + c1.w;
    float q = c0.x * c0.x + c0.y * c0.y + c0.z * c0.z + c0.w * c0.w
            + c1.x * c1.x + c1.y * c1.y + c1.z * c1.z + c1.w * c1.w;
    float4 p0, p1;
    float sp = 0.f, qp = 0.f;
    if (t > 0) {
        const float4* pr = (const float4*)(x + (size_t)(t - 1) * C_DIM);
        p0 = pr[tid * 2]; p1 = pr[tid * 2 + 1];
        sp = p0.x + p0.y + p0.z + p0.w + p1.x + p1.y + p1.z + p1.w;
        qp = p0.x * p0.x + p0.y * p0.y + p0.z * p0.z + p0.w * p0.w
           + p1.x * p1.x + p1.y * p1.y + p1.z * p1.z + p1.w * p1.w;
    } else {
        const float4* pr = (const float4*)sh;
        p0 = pr[tid * 2]; p1 = pr[tid * 2 + 1];
    }
    #pragma unroll
    for (int off = 32; off > 0; off >>= 1) {
        s += __shfl_down(s, off);   q += __shfl_down(q, off);
        sp += __shfl_down(sp, off); qp += __shfl_down(qp, off);
    }
    const int lane = tid & 63, wv = tid >> 6;
    if (lane == 0) { red[wv] = s; red[4 + wv] = q; red[8 + wv] = sp; red[12 + wv] = qp; }
    __syncthreads();
    if (tid == 0) {
        red[0] += red[1] + red[2] + red[3];
        red[4] += red[5] + red[6] + red[7];
        red[8] += red[9] + red[10] + red[11];
        red[12] += red[13] + red[14] + red[15];
    }
    __syncthreads();
    const float mc = red[0] * (1.f / C_DIM);
    const float ic = rsqrtf(red[4] * (1.f / C_DIM) - mc * mc + 1e-5f);
    const float mp = red[8] * (1.f / C_DIM);
    const float ip = rsqrtf(red[12] * (1.f / C_DIM) - mp * mp + 1e-5f);
    const float4* w4 = (const float4*)w;
    const float4* b4 = (const float4*)b;
    #pragma unroll
    for (int j = 0; j < 2; ++j) {
        const int i4 = tid * 2 + j;
        float4 cv = j ? c1 : c0, pv = j ? p1 : p0;
        float4 wv4 = w4[i4], bv = b4[i4];
        float4 cl, pl;
        cl.x = (cv.x - mc) * ic * wv4.x + bv.x;
        cl.y = (cv.y - mc) * ic * wv4.y + bv.y;
        cl.z = (cv.z - mc) * ic * wv4.z + bv.z;
        cl.w = (cv.w - mc) * ic * wv4.w + bv.w;
        if (t > 0) {
            pl.x = (pv.x - mp) * ip * wv4.x + bv.x;
            pl.y = (pv.y - mp) * ip * wv4.y + bv.y;
            pl.z = (pv.z - mp) * ip * wv4.z + bv.z;
            pl.w = (pv.w - mp) * ip * wv4.w + bv.w;
        } else pl = pv;
        const size_t o = (size_t)t * (C_DIM / 4) + i4;
        float4 m;
        ushort4 r;
        m = ((const float4*)mk)[i4];
        r.x = f2bf(cl.x * m.x + pl.x * (1.f - m.x));
        r.y = f2bf(cl.y * m.y + pl.y * (1.f - m.y));
        r.z = f2bf(cl.z * m.z + pl.z * (1.f - m.z));
        r.w = f2bf(cl.w * m.w + pl.w * (1.f - m.w));
        ((ushort4*)xk)[o] = r;
        m = ((const float4*)mv)[i4];
        r.x = f2bf(cl.x * m.x + pl.x * (1.f - m.x));
        r.y = f2bf(cl.y * m.y + pl.y * (1.f - m.y));
        r.z = f2bf(cl.z * m.z + pl.z * (1.f - m.z));
        r.w = f2bf(cl.w * m.w + pl.w * (1.f - m.w));
        ((ushort4*)xv)[o] = r;
        m = ((const float4*)mr)[i4];
        r.x = f2bf(cl.x * m.x + pl.x * (1.f - m.x));
        r.y = f2bf(cl.y * m.y + pl.y * (1.f - m.y));
        r.z = f2bf(cl.z * m.z + pl.z * (1.f - m.z));
        r.w = f2bf(cl.w * m.w + pl.w * (1.f - m.w));
        ((ushort4*)xr)[o] = r;
    }
}

// ---------- fused LayerNorm + token-shift mix (2 outputs) ----------
__global__ __launch_bounds__(256) void ln_mix2(
        const float* __restrict__ x, const float* __restrict__ sh,
        const float* __restrict__ w, const float* __restrict__ b,
        const float* __restrict__ mk, const float* __restrict__ mr,
        u16* __restrict__ fk, u16* __restrict__ fr) {
    __shared__ float red[16];
    const int t = blockIdx.x, tid = threadIdx.x;
    const float4* cr = (const float4*)(x + (size_t)t * C_DIM);
    float4 c0 = cr[tid * 2], c1 = cr[tid * 2 + 1];
    float s = c0.x + c0.y + c0.z + c0.w + c1.x + c1.y + c1.z + c1.w;
    float q = c0.x * c0.x + c0.y * c0.y + c0.z * c0.z + c0.w * c0.w
            + c1.x * c1.x + c1.y * c1.y + c1.z * c1.z + c1.w * c1.w;
    float4 p0, p1;
    float sp = 0.f, qp = 0.f;
    if (t > 0) {
        const float4* pr = (const float4*)(x + (size_t)(t - 1) * C_DIM);
        p0 = pr[tid * 2]; p1 = pr[tid * 2 + 1];
        sp = p0.x + p0.y + p0.z + p0.w + p1.x + p1.y + p1.z + p1.w;
        qp = p0.x * p0.x + p0.y * p0.y + p0.z * p0.z + p0.w * p0.w
           + p1.x * p1.x + p1.y * p1.y + p1.z * p1.z + p1.w * p1.w;
    } else {
        const float4* pr = (const float4*)sh;
        p0 = pr[tid * 2]; p1 = pr[tid * 2 + 1];
    }
    #pragma unroll
    for (int off = 32; off > 0; off >>= 1) {
        s += __shfl_down(s, off);   q += __shfl_down(q, off);
        sp += __shfl_down(sp, off); qp += __shfl_down(qp, off);
    }
    const int lane = tid & 63, wv = tid >> 6;
    if (lane == 0) { red[wv] = s; red[4 + wv] = q; red[8 + wv] = sp; red[12 + wv] = qp; }
    __syncthreads();
    if (tid == 0) {
        red[0] += red[1] + red[2] + red[3];
        red[4] += red[5] + red[6] + red[7];
        red[8] += red[9] + red[10] + red[11];
        red[12] += red[13] + red[14] + red[15];
    }
    __syncthreads();
    const float mc = red[0] * (1.f / C_DIM);
    const float ic = rsqrtf(red[4] * (1.f / C_DIM) - mc * mc + 1e-5f);
    const float mp = red[8] * (1.f / C_DIM);
    const float ip = rsqrtf(red[12] * (1.f / C_DIM) - mp * mp + 1e-5f);
    const float4* w4 = (const float4*)w;
    const float4* b4 = (const float4*)b;
    #pragma unroll
    for (int j = 0; j < 2; ++j) {
        const int i4 = tid * 2 + j;
        float4 cv = j ? c1 : c0, pv = j ? p1 : p0;
        float4 wv4 = w4[i4], bv = b4[i4];
        float4 cl, pl;
        cl.x = (cv.x - mc) * ic * wv4.x + bv.x;
        cl.y = (cv.y - mc) * ic * wv4.y + bv.y;
        cl.z = (cv.z - mc) * ic * wv4.z + bv.z;
        cl.w = (cv.w - mc) * ic * wv4.w + bv.w;
        if (t > 0) {
            pl.x = (pv.x - mp) * ip * wv4.x + bv.x;
            pl.y = (pv.y - mp) * ip * wv4.y + bv.y;
            pl.z = (pv.z - mp) * ip * wv4.z + bv.z;
            pl.w = (pv.w - mp) * ip * wv4.w + bv.w;
        } else pl = pv;
        const size_t o = (size_t)t * (C_DIM / 4) + i4;
        float4 m;
        ushort4 r;
        m = ((const float4*)mk)[i4];
        r.x = f2bf(cl.x * m.x + pl.x * (1.f - m.x));
        r.y = f2bf(cl.y * m.y + pl.y * (1.f - m.y));
        r.z = f2bf(cl.z * m.z + pl.z * (1.f - m.z));
        r.w = f2bf(cl.w * m.w + pl.w * (1.f - m.w));
        ((ushort4*)fk)[o] = r;
        m = ((const float4*)mr)[i4];
        r.x = f2bf(cl.x * m.x + pl.x * (1.f - m.x));
        r.y = f2bf(cl.y * m.y + pl.y * (1.f - m.y));
        r.z = f2bf(cl.z * m.z + pl.z * (1.f - m.z));
        r.w = f2bf(cl.w * m.w + pl.w * (1.f - m.w));
        ((ushort4*)fr)[o] = r;
    }
}

// ---------- f32 -> bf16 conversion ----------
__global__ __launch_bounds__(256) void cvt_bf16(const float* __restrict__ in,
                                                u16* __restrict__ out, int n8) {
    int i = blockIdx.x * 256 + threadIdx.x;
    const int stride = gridDim.x * 256;
    for (; i < n8; i += stride) {
        const float4* p = (const float4*)(in + (size_t)i * 8);
        float4 a = p[0], b = p[1];
        ushort4 lo, hi;
        lo.x = f2bf(a.x); lo.y = f2bf(a.y); lo.z = f2bf(a.z); lo.w = f2bf(a.w);
        hi.x = f2bf(b.x); hi.y = f2bf(b.y); hi.z = f2bf(b.z); hi.w = f2bf(b.w);
        ((ushort4*)out)[i * 2] = lo;
        ((ushort4*)out)[i * 2 + 1] = hi;
    }
}

// four C*C weights in one launch (blockIdx.y selects the array)
__global__ __launch_bounds__(256) void cvt4_bf16(const float* __restrict__ i0,
                                                 const float* __restrict__ i1,
                                                 const float* __restrict__ i2,
                                                 const float* __restrict__ i3,
                                                 u16* __restrict__ out, int n8) {
    const int sel = blockIdx.y;
    const float* in = sel == 0 ? i0 : (sel == 1 ? i1 : (sel == 2 ? i2 : i3));
    u16* o = out + (size_t)sel * n8 * 8;
    int i = blockIdx.x * 256 + threadIdx.x;
    const int stride = gridDim.x * 256;
    for (; i < n8; i += stride) {
        const float4* p = (const float4*)(in + (size_t)i * 8);
        float4 a = p[0], b = p[1];
        ushort4 lo, hi;
        lo.x = f2bf(a.x); lo.y = f2bf(a.y); lo.z = f2bf(a.z); lo.w = f2bf(a.w);
        hi.x = f2bf(b.x); hi.y = f2bf(b.y); hi.z = f2bf(b.z); hi.w = f2bf(b.w);
        ((ushort4*)o)[i * 2] = lo;
        ((ushort4*)o)[i * 2 + 1] = hi;
    }
}

// ---------- WKV parallel scan ----------
__global__ __launch_bounds__(256) void wkv_part(const float* __restrict__ td,
                                                const float* __restrict__ k,
                                                const float* __restrict__ v,
                                                float* __restrict__ Ab,
                                                float* __restrict__ Bb) {
    const int idx = blockIdx.x * 256 + threadIdx.x;     // C*P threads
    const int c = idx & (C_DIM - 1);
    const int p = idx >> 11;
    const float ew = expf(-expf(td[c]));
    float A = 0.f, B = 0.f;
    size_t o = (size_t)(p * WKV_L) * C_DIM + c;
    #pragma unroll 4
    for (int i = 0; i < WKV_L; ++i, o += C_DIM) {
        const float kk = expf(k[o]);
        A = (A + kk * v[o]) * ew;
        B = (B + kk) * ew;
    }
    Ab[p * C_DIM + c] = A;
    Bb[p * C_DIM + c] = B;
}

__global__ __launch_bounds__(256) void wkv_comb(const float* __restrict__ td,
                                                const float* __restrict__ st,
                                                const float* __restrict__ Ab,
                                                const float* __restrict__ Bb,
                                                float* __restrict__ Sa,
                                                float* __restrict__ Sb) {
    const int c = blockIdx.x * 256 + threadIdx.x;       // C threads
    const float w = -expf(td[c]);
    const float dL = expf(w * (float)WKV_L);            // ew^L
    float a = st[c];
    float b = st[C_DIM + c];
    #pragma unroll 4
    for (int p = 0; p < WKV_P; ++p) {
        Sa[p * C_DIM + c] = a;
        Sb[p * C_DIM + c] = b;
        a = dL * a + Ab[p * C_DIM + c];
        b = dL * b + Bb[p * C_DIM + c];
    }
}

__global__ __launch_bounds__(256) void wkv_emit(const float* __restrict__ td,
                                                const float* __restrict__ tf,
                                                const float* __restrict__ k,
                                                const float* __restrict__ v,
                                                const float* __restrict__ r,
                                                const float* __restrict__ Sa,
                                                const float* __restrict__ Sb,
                                                u16* __restrict__ pout) {
    const int idx = blockIdx.x * 256 + threadIdx.x;     // C*P threads
    const int c = idx & (C_DIM - 1);
    const int p = idx >> 11;
    const float u = tf[c];
    const float w = -expf(td[c]);
    const float ew = expf(w);
    float a = Sa[p * C_DIM + c];
    float b = Sb[p * C_DIM + c];
    size_t o = (size_t)(p * WKV_L) * C_DIM + c;
    #pragma unroll 2
    for (int i = 0; i < WKV_L; ++i, o += C_DIM) {
        const float kt = k[o], vt = v[o], rt = r[o];
        const float e = expf(u + w + kt);
        const float y = (a + e * vt) / (b + e);
        const float kk = expf(kt);
        a = (a + kk * vt) * ew;
        b = (b + kk) * ew;
        const float sr = 1.f / (1.f + expf(-rt));
        pout[o] = f2bf(sr * y);
    }
}

enum { EPI_F32 = 0, EPI_ADDX = 1, EPI_RELU2 = 2, EPI_SIGMULADD = 3, EPI_SIGMULADD4 = 4 };

// ---------- 128x128 bf16 NT GEMM — 3-slot pipeline (R9, proven) ----------
template <int EPI>
__global__ __launch_bounds__(256, 3) void gemm_bt(
        const u16* __restrict__ A, int lda, long a_zs,
        const u16* __restrict__ B, int ldb, long b_zs,
        long koff, int Kloop,
        void* __restrict__ outp, int ldo, long o_zs,
        const float* __restrict__ aux1, const float* __restrict__ aux2) {
    __shared__ u16 lds[3 * 8192];   // 48 KiB: 3 slots x (A 8KB + B 8KB)
    const int tid = threadIdx.x;
    const int l = tid & 63, w = tid >> 6;
    const int wr2 = w >> 1, wc2 = w & 1;     // 2x2 waves of 64x64

    const int gx = gridDim.x, gy = gridDim.y;
    const int nxy = gx * gy;
    const int flat = (blockIdx.z * gy + blockIdx.y) * gx + blockIdx.x;
    const int cpx = (nxy * gridDim.z) >> 3;
    const int swz = (flat & 7) * cpx + (flat >> 3);
    const int z = swz / nxy;
    const int rem = swz - z * nxy;
    const int bm = rem % gy;
    const int bn = rem / gy;

    const u16* Ag = A + (size_t)z * a_zs + (size_t)z * koff + (size_t)bm * 128 * lda;
    const u16* Bg = B + (size_t)z * b_zs + (size_t)z * koff + (size_t)bn * 128 * ldb;

    long gA[2], gB[2];
    int dA[2], dB[2];
    #pragma unroll
    for (int j = 0; j < 2; ++j) {
        const int off = j * 4096 + w * 1024 + l * 16;
        const int row = off >> 6;
        const int cb = (off & 63) ^ (((off >> 9) & 1) << 5);
        gA[j] = (long)row * lda + (cb >> 1);
        gB[j] = (long)row * ldb + (cb >> 1);
        dA[j] = j * 2048 + w * 512;
        dB[j] = 4096 + j * 2048 + w * 512;
    }

    int offA[4], offB[4];
    #pragma unroll
    for (int m = 0; m < 4; ++m) {
        const int lin = (wr2 * 64 + m * 16 + (l & 15)) * 64 + ((l >> 4) << 4);
        offA[m] = (lin ^ (((lin >> 9) & 1) << 5)) >> 1;
    }
    #pragma unroll
    for (int n = 0; n < 4; ++n) {
        const int lin = (wc2 * 64 + n * 16 + (l & 15)) * 64 + ((l >> 4) << 4);
        offB[n] = 4096 + ((lin ^ (((lin >> 9) & 1) << 5)) >> 1);
    }

    const f32x4 fz = {0.f, 0.f, 0.f, 0.f};
    f32x4 acc[4][4];
    #pragma unroll
    for (int m = 0; m < 4; ++m)
        #pragma unroll
        for (int n = 0; n < 4; ++n) acc[m][n] = fz;

    const int NT = Kloop >> 5;

    auto stage = [&](int kt, int sp) {
        const long ko = (long)kt << 5;
        const int sb = sp * 8192;
        async16(Ag + gA[0] + ko, &lds[sb + dA[0]]);
        async16(Ag + gA[1] + ko, &lds[sb + dA[1]]);
        async16(Bg + gB[0] + ko, &lds[sb + dB[0]]);
        async16(Bg + gB[1] + ko, &lds[sb + dB[1]]);
    };

    stage(0, 0);
    stage(1, 1);

    int sr = 0;
    for (int t = 0; t < NT; ++t) {
        asm volatile("s_waitcnt vmcnt(4)" ::: "memory");
        __builtin_amdgcn_s_barrier();
        __builtin_amdgcn_sched_barrier(0);
        {
            const int tp = (t + 2 < NT) ? t + 2 : NT - 1;
            const int sp = (sr == 0) ? 2 : sr - 1;
            stage(tp, sp);
        }
        const int sb = sr * 8192;
        bf16x8 af[4], bfv[4];
        #pragma unroll
        for (int m = 0; m < 4; ++m) af[m] = *(const bf16x8*)&lds[sb + offA[m]];
        #pragma unroll
        for (int n = 0; n < 4; ++n) bfv[n] = *(const bf16x8*)&lds[sb + offB[n]];
        __builtin_amdgcn_s_setprio(1);
        #pragma unroll
        for (int m = 0; m < 2; ++m)
            #pragma unroll
            for (int n = 0; n < 4; ++n)
                acc[m][n] = __builtin_amdgcn_mfma_f32_16x16x32_bf16(af[m], bfv[n], acc[m][n], 0, 0, 0);
        __builtin_amdgcn_s_setprio(0);
        __builtin_amdgcn_s_setprio(1);
        #pragma unroll
        for (int m = 2; m < 4; ++m)
            #pragma unroll
            for (int n = 0; n < 4; ++n)
                acc[m][n] = __builtin_amdgcn_mfma_f32_16x16x32_bf16(af[m], bfv[n], acc[m][n], 0, 0, 0);
        __builtin_amdgcn_s_setprio(0);
        sr = (sr == 2) ? 0 : sr + 1;
    }
    asm volatile("s_waitcnt vmcnt(0)" ::: "memory");

    const int r00 = bm * 128 + wr2 * 64 + ((l >> 4) << 2);
    const int c00 = bn * 128 + wc2 * 64 + (l & 15);
    #pragma unroll
    for (int m = 0; m < 4; ++m) {
        #pragma unroll
        for (int n = 0; n < 4; ++n) {
            #pragma unroll
            for (int j = 0; j < 4; ++j) {
                const int rr = r00 + m * 16 + j;
                const int cc = c00 + n * 16;
                const size_t o = (size_t)rr * ldo + cc;
                const float val = acc[m][n][j];
                if constexpr (EPI == EPI_F32) {
                    ((float*)outp)[(size_t)z * o_zs + o] = val;
                } else if constexpr (EPI == EPI_ADDX) {
                    ((float*)outp)[o] = aux1[o] + val;
                } else if constexpr (EPI == EPI_RELU2) {
                    const float tp2 = fmaxf(val, 0.f);
                    ((u16*)outp)[o] = f2bf(tp2 * tp2);
                } else if constexpr (EPI == EPI_SIGMULADD) {
                    const float sg = 1.f / (1.f + expf(-val));
                    ((float*)outp)[o] = aux1[o] + sg * aux2[o];
                } else {  // EPI_SIGMULADD4: aux2 = 4 split-K partials, fused sum
                    const float kv = aux2[o]
                                   + aux2[o + (size_t)T_DIM * C_DIM]
                                   + aux2[o + 2 * (size_t)T_DIM * C_DIM]
                                   + aux2[o + 3 * (size_t)T_DIM * C_DIM];
                    const float sg = 1.f / (1.f + expf(-val));
                    ((float*)outp)[o] = aux1[o] + sg * kv;
                }
            }
        }
    }
}

// ---------- 256x256 bf16 NT GEMM — 4-buffer deep-prefetch (R14, proven) ----
template <int EPI>
__global__ __launch_bounds__(512, 2) void gemm4s(
        const u16* __restrict__ A, int lda,
        const u16* __restrict__ B, int ldb,
        long koff, int Kloop,
        void* __restrict__ outp, int ldo, long o_zs) {
    __shared__ u16 lds[4 * 16384];   // 128 KiB
    const int tid = threadIdx.x;
    const int l = tid & 63, w = tid >> 6;
    const int wm = w >> 2, wn = w & 3;

    const int gx = gridDim.x, gy = gridDim.y;
    const int nxy = gx * gy;
    const int flat = (blockIdx.z * gy + blockIdx.y) * gx + blockIdx.x;
    const int cpx = (nxy * gridDim.z) >> 3;
    const int swzb = (flat & 7) * cpx + (flat >> 3);
    const int z = swzb / nxy;
    const int rem = swzb - z * nxy;
    const int bm = rem % gy;
    const int bn = rem / gy;

    const u16* Ag = A + (size_t)z * koff + (size_t)bm * 256 * lda;
    const u16* Bg = B + (size_t)z * koff + (size_t)bn * 256 * ldb;

    long srcA[2], srcB[2];
    int dstA[2], dstB[2];
    #pragma unroll
    for (int h = 0; h < 2; ++h) {
        const int off = h * 8192 + w * 1024 + l * 16;   // byte in 16KB region
        const int row = off >> 6;                        // 64B rows
        const int cbyte = (off & 63) ^ (((off >> 9) & 1) << 5);
        srcA[h] = (long)row * lda + (cbyte >> 1);
        srcB[h] = (long)row * ldb + (cbyte >> 1);
        dstA[h] = off >> 1;
        dstB[h] = 8192 + (off >> 1);
    }

    int offAL[4], offAH[4], offB[4];
    #pragma unroll
    for (int mi = 0; mi < 4; ++mi) {
        int row = wm * 128 + mi * 16 + (l & 15);
        int lin = row * 64 + ((l >> 4) << 4);
        offAL[mi] = (lin ^ (((lin >> 9) & 1) << 5)) >> 1;
        lin = (row + 64) * 64 + ((l >> 4) << 4);
        offAH[mi] = (lin ^ (((lin >> 9) & 1) << 5)) >> 1;
    }
    #pragma unroll
    for (int n = 0; n < 4; ++n) {
        const int row = wn * 64 + n * 16 + (l & 15);
        const int lin = row * 64 + ((l >> 4) << 4);
        offB[n] = 8192 + ((lin ^ (((lin >> 9) & 1) << 5)) >> 1);
    }

    const f32x4 fz = {0.f, 0.f, 0.f, 0.f};
    f32x4 acc[8][4];
    #pragma unroll
    for (int m = 0; m < 8; ++m)
        #pragma unroll
        for (int n = 0; n < 4; ++n) acc[m][n] = fz;

    const int NT = Kloop >> 5;          // K-tiles of 32 (>=4, even at all sites)

    auto stgA = [&](int kt, int buf, int h) {
        async16(Ag + srcA[h] + (long)kt * 32, &lds[buf * 16384 + dstA[h]]);
    };
    auto stgB = [&](int kt, int buf, int h) {
        async16(Bg + srcB[h] + (long)kt * 32, &lds[buf * 16384 + dstB[h]]);
    };

    // prologue: tiles 0,1,2 staged (12 loads); vmcnt(8) -> tile 0 landed
    stgA(0, 0, 0); stgA(0, 0, 1); stgB(0, 0, 0); stgB(0, 0, 1);
    stgA(1, 1, 0); stgA(1, 1, 1); stgB(1, 1, 0); stgB(1, 1, 1);
    stgA(2, 2, 0); stgA(2, 2, 1); stgB(2, 2, 0); stgB(2, 2, 1);
    asm volatile("s_waitcnt vmcnt(8)" ::: "memory");
    __builtin_amdgcn_s_barrier();

    bf16x8 aX[4], bX[4], aY[4], bY[4];
    #pragma unroll
    for (int mi = 0; mi < 4; ++mi) aX[mi] = *(const bf16x8*)&lds[offAL[mi]];
    #pragma unroll
    for (int n = 0; n < 4; ++n) bX[n] = *(const bf16x8*)&lds[offB[n]];

    auto tile = [&](int kt, bf16x8 (&aC)[4], bf16x8 (&bbC)[4],
                    bf16x8 (&aN)[4], bf16x8 (&bbN)[4]) {
        const int cb = (kt & 3) * 16384;
        const int nb = ((kt + 1) & 3) * 16384;
        const int tb = (kt + 3) & 3;
        const int ksrc = (kt + 3 < NT) ? kt + 3 : NT - 1;
        bf16x8 aH[4];
        // ---- ph0: read m4-7 (cur buf) | stage A halves of kt+3 ----
        #pragma unroll
        for (int mi = 0; mi < 4; ++mi) aH[mi] = *(const bf16x8*)&lds[cb + offAH[mi]];
        stgA(ksrc, tb, 0); stgA(ksrc, tb, 1);
        __builtin_amdgcn_s_barrier();
        asm volatile("s_waitcnt lgkmcnt(4)" ::: "memory");   // prev-phase reads done
        __builtin_amdgcn_sched_barrier(0);
        __builtin_amdgcn_s_setprio(1);
        #pragma unroll
        for (int mi = 0; mi < 4; ++mi)
            #pragma unroll
            for (int n = 0; n < 4; ++n)
                acc[mi][n] = __builtin_amdgcn_mfma_f32_16x16x32_bf16(aC[mi], bbC[n], acc[mi][n], 0, 0, 0);
        __builtin_amdgcn_s_setprio(0);
        // deep-prefetch checkpoint: newest 6 loads {A(kt+3),B(kt+2),A(kt+2)}
        // may remain; tile kt+1 fully landed. Barrier orders cross-wave.
        asm volatile("s_waitcnt vmcnt(6)" ::: "memory");
        __builtin_amdgcn_s_barrier();
        // ---- ph1: read next tile m0-3+B (next buf) | stage B halves of kt+3 --
        #pragma unroll
        for (int mi = 0; mi < 4; ++mi) aN[mi] = *(const bf16x8*)&lds[nb + offAL[mi]];
        #pragma unroll
        for (int n = 0; n < 4; ++n) bbN[n] = *(const bf16x8*)&lds[nb + offB[n]];
        stgB(ksrc, tb, 0); stgB(ksrc, tb, 1);
        __builtin_amdgcn_s_barrier();
        asm volatile("s_waitcnt lgkmcnt(8)" ::: "memory");   // ph0's aH done
        __builtin_amdgcn_sched_barrier(0);
        __builtin_amdgcn_s_setprio(1);
        #pragma unroll
        for (int mi = 0; mi < 4; ++mi)
            #pragma unroll
            for (int n = 0; n < 4; ++n)
                acc[4 + mi][n] = __builtin_amdgcn_mfma_f32_16x16x32_bf16(aH[mi], bbC[n], acc[4 + mi][n], 0, 0, 0);
        __builtin_amdgcn_s_setprio(0);
        __builtin_amdgcn_s_barrier();
    };

    for (int kt = 0; kt < NT; kt += 2) {
        tile(kt, aX, bX, aY, bY);
        tile(kt + 1, aY, bY, aX, bX);
    }
    asm volatile("s_waitcnt vmcnt(0)" ::: "memory");  // drain tail stages

    // --- epilogue (verified 256²/8-wave mapping) ---
    const int r00 = bm * 256 + wm * 128 + ((l >> 4) << 2);
    const int c00 = bn * 256 + wn * 64 + (l & 15);
    #pragma unroll
    for (int m = 0; m < 8; ++m) {
        #pragma unroll
        for (int n = 0; n < 4; ++n) {
            #pragma unroll
            for (int j = 0; j < 4; ++j) {
                const int rr = r00 + m * 16 + j;
                const int cc = c00 + n * 16;
                const size_t o = (size_t)rr * ldo + cc;
                const float val = acc[m][n][j];
                if constexpr (EPI == EPI_F32) {
                    ((float*)outp)[(size_t)z * o_zs + o] = val;
                } else {  // EPI_RELU2
                    const float tp2 = fmaxf(val, 0.f);
                    ((u16*)outp)[o] = f2bf(tp2 * tp2);
                }
            }
        }
    }
}

// ---------- launcher ----------
extern "C" void kernel_launch(void* const* d_in, const int* in_sizes, int n_in,
                              void* d_out, int out_size, void* d_ws, size_t ws_size,
                              hipStream_t stream) {
    const float* x         = (const float*)d_in[0];
    const float* att_shift = (const float*)d_in[1];
    const float* wkv_state = (const float*)d_in[2];
    const float* ffn_shift = (const float*)d_in[3];
    const float* ln1w = (const float*)d_in[4];
    const float* ln1b = (const float*)d_in[5];
    const float* ln2w = (const float*)d_in[6];
    const float* ln2b = (const float*)d_in[7];
    const float* tmk  = (const float*)d_in[8];
    const float* tmv  = (const float*)d_in[9];
    const float* tmr  = (const float*)d_in[10];
    const float* td   = (const float*)d_in[11];
    const float* tf   = (const float*)d_in[12];
    const float* Wk   = (const float*)d_in[13];
    const float* Wv   = (const float*)d_in[14];
    const float* Wr   = (const float*)d_in[15];
    const float* Wo   = (const float*)d_in[16];
    const float* ftmk = (const float*)d_in[17];
    const float* ftmr = (const float*)d_in[18];
    const float* Wfk  = (const float*)d_in[19];   // [F, C]
    const float* Wfv  = (const float*)d_in[20];   // [C, F]
    const float* Wfr  = (const float*)d_in[21];   // [C, C]
    float* out = (float*)d_out;

    char* ws = (char*)d_ws;
    const size_t MB = 1ull << 20;
    u16*   xk  = (u16*)(ws + 16 * MB);        // 8 MB bf16       (also fk)
    u16*   xv  = (u16*)(ws + 24 * MB);        // 8 MB bf16       (also fr)
    u16*   xr  = (u16*)(ws + 32 * MB);        // 8 MB bf16
    float* kb  = (float*)(ws + 40 * MB);      // 16 MB f32
    float* vb  = (float*)(ws + 56 * MB);      // 16 MB f32
    float* rb  = (float*)(ws + 72 * MB);      // 16 MB f32
    u16*   pb  = (u16*)(ws + 88 * MB);        // 8 MB bf16
    float* x1  = (float*)(ws + 96 * MB);      // 16 MB f32
    u16*   kf  = (u16*)(ws + 112 * MB);       // 32 MB bf16 [T,F]
    u16*   Wb  = (u16*)(ws + 144 * MB);       // 32 MB bf16 weight scratch
    // wkv scratch overlays kf region (dead during TimeMix):
    float* wAb = (float*)(ws + 112 * MB);
    float* wBb = (float*)(ws + 112 * MB + 512 * 1024);
    float* wSa = (float*)(ws + 113 * MB);
    float* wSb = (float*)(ws + 113 * MB + 512 * 1024);
    // ffn_value split-K partials: 4 x 16 MB in [32,96) (xr/kb/vb/rb/pb dead);
    // consumed directly by the recept GEMM's EPI_SIGMULADD4 epilogue.
    float* fvp = (float*)(ws + 32 * MB);

    const int T = T_DIM, C = C_DIM, F = F_DIM;
    const dim3 blk(256), blk5(512);

    // --- TimeMix ---
    ln_mix3<<<T, blk, 0, stream>>>(x, att_shift, ln1w, ln1b, tmk, tmv, tmr, xk, xv, xr);

    // all four CxC weights in one launch: Wb = [Wk|Wv|Wr|Wo]
    cvt4_bf16<<<dim3(1024, 4), blk, 0, stream>>>(Wk, Wv, Wr, Wo, Wb, C * C / 8);
    // batched qkv: grid 16x16x3 = 768 blocks (128² kernel)
    gemm_bt<EPI_F32><<<dim3(C / 128, T / 128, 3), blk, 0, stream>>>(
        xk, C, (long)T * C, Wb, C, (long)C * C, 0, C,
        kb, C, (long)T * C, nullptr, nullptr);

    wkv_part<<<(C * WKV_P) / 256, blk, 0, stream>>>(td, kb, vb, wAb, wBb);
    wkv_comb<<<C / 256, blk, 0, stream>>>(td, wkv_state, wAb, wBb, wSa, wSb);
    wkv_emit<<<(C * WKV_P) / 256, blk, 0, stream>>>(td, tf, kb, vb, rb, wSa, wSb, pb);

    // att_out fused +x: 256 blocks (Wo already converted at Wb+3*C*C)
    gemm_bt<EPI_ADDX><<<dim3(C / 128, T / 128, 1), blk, 0, stream>>>(
        pb, C, 0, Wb + 3 * (size_t)C * C, C, 0, 0, C, x1, C, 0, x, nullptr);

    // --- ChannelMix ---
    ln_mix2<<<T, blk, 0, stream>>>(x1, ffn_shift, ln2w, ln2b, ftmk, ftmr, xk, xv);

    cvt_bf16<<<2048, blk, 0, stream>>>(Wfk, Wb, F * C / 8);
    // ffn_key on 256² deep-prefetch kernel: grid 32x8 = 256 blocks
    gemm4s<EPI_RELU2><<<dim3(F / 256, T / 256, 1), blk5, 0, stream>>>(
        xk, C, Wb, C, 0, C, kf, F, 0);

    cvt_bf16<<<2048, blk, 0, stream>>>(Wfv, Wb, C * F / 8);
    // ffn_value on 256², split-K x4 (koff=2048): 256 blocks -> 4 partials
    gemm4s<EPI_F32><<<dim3(C / 256, T / 256, 4), blk5, 0, stream>>>(
        kf, F, Wb, F, 2048, 2048, fvp, C, (long)T * C);

    cvt_bf16<<<2048, blk, 0, stream>>>(Wfr, Wb, C * C / 8);
    // ffn_recept fused: sigmoid(gemm) * (sum of 4 partials) + x1
    gemm_bt<EPI_SIGMULADD4><<<dim3(C / 128, T / 128, 1), blk, 0, stream>>>(
        xv, C, 0, Wb, C, 0, 0, C, out, C, 0, x1, fvp);
}

// Round 16
// 378.460 us; speedup vs baseline: 1.0470x; 1.0082x over previous
//
#include <hip/hip_runtime.h>
#include <hip/hip_bf16.h>

typedef unsigned short u16;
typedef short bf16x8 __attribute__((ext_vector_type(8)));
typedef float f32x4 __attribute__((ext_vector_type(4)));

#define T_DIM 2048
#define C_DIM 2048
#define F_DIM 8192
#define WKV_L 32
#define WKV_P (T_DIM / WKV_L)   // 64 chunks

// ---------- helpers ----------
__device__ __forceinline__ u16 f2bf(float f) {
    unsigned int u = __float_as_uint(f);
    u += 0x7fff + ((u >> 16) & 1);          // round-to-nearest-even
    return (u16)(u >> 16);
}

__device__ __forceinline__ float b2f(u16 v) {
    return __uint_as_float((unsigned int)v << 16);
}

__device__ __forceinline__ void async16(const void* g, void* l) {
    __builtin_amdgcn_global_load_lds(
        (__attribute__((address_space(1))) const unsigned int*)g,
        (__attribute__((address_space(3))) unsigned int*)l, 16, 0, 0);
}

// ---------- fused LayerNorm + token-shift mix (3 outputs) ----------
__global__ __launch_bounds__(256) void ln_mix3(
        const float* __restrict__ x, const float* __restrict__ sh,
        const float* __restrict__ w, const float* __restrict__ b,
        const float* __restrict__ mk, const float* __restrict__ mv,
        const float* __restrict__ mr,
        u16* __restrict__ xk, u16* __restrict__ xv, u16* __restrict__ xr) {
    __shared__ float red[16];
    const int t = blockIdx.x, tid = threadIdx.x;
    const float4* cr = (const float4*)(x + (size_t)t * C_DIM);
    float4 c0 = cr[tid * 2], c1 = cr[tid * 2 + 1];
    float s = c0.x + c0.y + c0.z + c0.w + c1.x + c1.y + c1.z + c1.w;
    float q = c0.x * c0.x + c0.y * c0.y + c0.z * c0.z + c0.w * c0.w
            + c1.x * c1.x + c1.y * c1.y + c1.z * c1.z + c1.w * c1.w;
    float4 p0, p1;
    float sp = 0.f, qp = 0.f;
    if (t > 0) {
        const float4* pr = (const float4*)(x + (size_t)(t - 1) * C_DIM);
        p0 = pr[tid * 2]; p1 = pr[tid * 2 + 1];
        sp = p0.x + p0.y + p0.z + p0.w + p1.x + p1.y + p1.z + p1.w;
        qp = p0.x * p0.x + p0.y * p0.y + p0.z * p0.z + p0.w * p0.w
           + p1.x * p1.x + p1.y * p1.y + p1.z * p1.z + p1.w * p1.w;
    } else {
        const float4* pr = (const float4*)sh;
        p0 = pr[tid * 2]; p1 = pr[tid * 2 + 1];
    }
    #pragma unroll
    for (int off = 32; off > 0; off >>= 1) {
        s += __shfl_down(s, off);   q += __shfl_down(q, off);
        sp += __shfl_down(sp, off); qp += __shfl_down(qp, off);
    }
    const int lane = tid & 63, wv = tid >> 6;
    if (lane == 0) { red[wv] = s; red[4 + wv] = q; red[8 + wv] = sp; red[12 + wv] = qp; }
    __syncthreads();
    if (tid == 0) {
        red[0] += red[1] + red[2] + red[3];
        red[4] += red[5] + red[6] + red[7];
        red[8] += red[9] + red[10] + red[11];
        red[12] += red[13] + red[14] + red[15];
    }
    __syncthreads();
    const float mc = red[0] * (1.f / C_DIM);
    const float ic = rsqrtf(red[4] * (1.f / C_DIM) - mc * mc + 1e-5f);
    const float mp = red[8] * (1.f / C_DIM);
    const float ip = rsqrtf(red[12] * (1.f / C_DIM) - mp * mp + 1e-5f);
    const float4* w4 = (const float4*)w;
    const float4* b4 = (const float4*)b;
    #pragma unroll
    for (int j = 0; j < 2; ++j) {
        const int i4 = tid * 2 + j;
        float4 cv = j ? c1 : c0, pv = j ? p1 : p0;
        float4 wv4 = w4[i4], bv = b4[i4];
        float4 cl, pl;
        cl.x = (cv.x - mc) * ic * wv4.x + bv.x;
        cl.y = (cv.y - mc) * ic * wv4.y + bv.y;
        cl.z = (cv.z - mc) * ic * wv4.z + bv.z;
        cl.w = (cv.w - mc) * ic * wv4.w + bv.w;
        if (t > 0) {
            pl.x = (pv.x - mp) * ip * wv4.x + bv.x;
            pl.y = (pv.y - mp) * ip * wv4.y + bv.y;
            pl.z = (pv.z - mp) * ip * wv4.z + bv.z;
            pl.w = (pv.w - mp) * ip * wv4.w + bv.w;
        } else pl = pv;
        const size_t o = (size_t)t * (C_DIM / 4) + i4;
        float4 m;
        ushort4 r;
        m = ((const float4*)mk)[i4];
        r.x = f2bf(cl.x * m.x + pl.x * (1.f - m.x));
        r.y = f2bf(cl.y * m.y + pl.y * (1.f - m.y));
        r.z = f2bf(cl.z * m.z + pl.z * (1.f - m.z));
        r.w = f2bf(cl.w * m.w + pl.w * (1.f - m.w));
        ((ushort4*)xk)[o] = r;
        m = ((const float4*)mv)[i4];
        r.x = f2bf(cl.x * m.x + pl.x * (1.f - m.x));
        r.y = f2bf(cl.y * m.y + pl.y * (1.f - m.y));
        r.z = f2bf(cl.z * m.z + pl.z * (1.f - m.z));
        r.w = f2bf(cl.w * m.w + pl.w * (1.f - m.w));
        ((ushort4*)xv)[o] = r;
        m = ((const float4*)mr)[i4];
        r.x = f2bf(cl.x * m.x + pl.x * (1.f - m.x));
        r.y = f2bf(cl.y * m.y + pl.y * (1.f - m.y));
        r.z = f2bf(cl.z * m.z + pl.z * (1.f - m.z));
        r.w = f2bf(cl.w * m.w + pl.w * (1.f - m.w));
        ((ushort4*)xr)[o] = r;
    }
}

// ---------- fused LayerNorm + token-shift mix (2 outputs) ----------
__global__ __launch_bounds__(256) void ln_mix2(
        const float* __restrict__ x, const float* __restrict__ sh,
        const float* __restrict__ w, const float* __restrict__ b,
        const float* __restrict__ mk, const float* __restrict__ mr,
        u16* __restrict__ fk, u16* __restrict__ fr) {
    __shared__ float red[16];
    const int t = blockIdx.x, tid = threadIdx.x;
    const float4* cr = (const float4*)(x + (size_t)t * C_DIM);
    float4 c0 = cr[tid * 2], c1 = cr[tid * 2 + 1];
    float s = c0.x + c0.y + c0.z + c0.w + c1.x + c1.y + c1.z + c1.w;
    float q = c0.x * c0.x + c0.y * c0.y + c0.z * c0.z + c0.w * c0.w
            + c1.x * c1.x + c1.y * c1.y + c1.z * c1.z + c1.w * c1.w;
    float4 p0, p1;
    float sp = 0.f, qp = 0.f;
    if (t > 0) {
        const float4* pr = (const float4*)(x + (size_t)(t - 1) * C_DIM);
        p0 = pr[tid * 2]; p1 = pr[tid * 2 + 1];
        sp = p0.x + p0.y + p0.z + p0.w + p1.x + p1.y + p1.z + p1.w;
        qp = p0.x * p0.x + p0.y * p0.y + p0.z * p0.z + p0.w * p0.w
           + p1.x * p1.x + p1.y * p1.y + p1.z * p1.z + p1.w * p1.w;
    } else {
        const float4* pr = (const float4*)sh;
        p0 = pr[tid * 2]; p1 = pr[tid * 2 + 1];
    }
    #pragma unroll
    for (int off = 32; off > 0; off >>= 1) {
        s += __shfl_down(s, off);   q += __shfl_down(q, off);
        sp += __shfl_down(sp, off); qp += __shfl_down(qp, off);
    }
    const int lane = tid & 63, wv = tid >> 6;
    if (lane == 0) { red[wv] = s; red[4 + wv] = q; red[8 + wv] = sp; red[12 + wv] = qp; }
    __syncthreads();
    if (tid == 0) {
        red[0] += red[1] + red[2] + red[3];
        red[4] += red[5] + red[6] + red[7];
        red[8] += red[9] + red[10] + red[11];
        red[12] += red[13] + red[14] + red[15];
    }
    __syncthreads();
    const float mc = red[0] * (1.f / C_DIM);
    const float ic = rsqrtf(red[4] * (1.f / C_DIM) - mc * mc + 1e-5f);
    const float mp = red[8] * (1.f / C_DIM);
    const float ip = rsqrtf(red[12] * (1.f / C_DIM) - mp * mp + 1e-5f);
    const float4* w4 = (const float4*)w;
    const float4* b4 = (const float4*)b;
    #pragma unroll
    for (int j = 0; j < 2; ++j) {
        const int i4 = tid * 2 + j;
        float4 cv = j ? c1 : c0, pv = j ? p1 : p0;
        float4 wv4 = w4[i4], bv = b4[i4];
        float4 cl, pl;
        cl.x = (cv.x - mc) * ic * wv4.x + bv.x;
        cl.y = (cv.y - mc) * ic * wv4.y + bv.y;
        cl.z = (cv.z - mc) * ic * wv4.z + bv.z;
        cl.w = (cv.w - mc) * ic * wv4.w + bv.w;
        if (t > 0) {
            pl.x = (pv.x - mp) * ip * wv4.x + bv.x;
            pl.y = (pv.y - mp) * ip * wv4.y + bv.y;
            pl.z = (pv.z - mp) * ip * wv4.z + bv.z;
            pl.w = (pv.w - mp) * ip * wv4.w + bv.w;
        } else pl = pv;
        const size_t o = (size_t)t * (C_DIM / 4) + i4;
        float4 m;
        ushort4 r;
        m = ((const float4*)mk)[i4];
        r.x = f2bf(cl.x * m.x + pl.x * (1.f - m.x));
        r.y = f2bf(cl.y * m.y + pl.y * (1.f - m.y));
        r.z = f2bf(cl.z * m.z + pl.z * (1.f - m.z));
        r.w = f2bf(cl.w * m.w + pl.w * (1.f - m.w));
        ((ushort4*)fk)[o] = r;
        m = ((const float4*)mr)[i4];
        r.x = f2bf(cl.x * m.x + pl.x * (1.f - m.x));
        r.y = f2bf(cl.y * m.y + pl.y * (1.f - m.y));
        r.z = f2bf(cl.z * m.z + pl.z * (1.f - m.z));
        r.w = f2bf(cl.w * m.w + pl.w * (1.f - m.w));
        ((ushort4*)fr)[o] = r;
    }
}

// ---------- f32 -> bf16 conversion ----------
__global__ __launch_bounds__(256) void cvt_bf16(const float* __restrict__ in,
                                                u16* __restrict__ out, int n8) {
    int i = blockIdx.x * 256 + threadIdx.x;
    const int stride = gridDim.x * 256;
    for (; i < n8; i += stride) {
        const float4* p = (const float4*)(in + (size_t)i * 8);
        float4 a = p[0], b = p[1];
        ushort4 lo, hi;
        lo.x = f2bf(a.x); lo.y = f2bf(a.y); lo.z = f2bf(a.z); lo.w = f2bf(a.w);
        hi.x = f2bf(b.x); hi.y = f2bf(b.y); hi.z = f2bf(b.z); hi.w = f2bf(b.w);
        ((ushort4*)out)[i * 2] = lo;
        ((ushort4*)out)[i * 2 + 1] = hi;
    }
}

// four C*C weights in one launch (blockIdx.y selects the array)
__global__ __launch_bounds__(256) void cvt4_bf16(const float* __restrict__ i0,
                                                 const float* __restrict__ i1,
                                                 const float* __restrict__ i2,
                                                 const float* __restrict__ i3,
                                                 u16* __restrict__ out, int n8) {
    const int sel = blockIdx.y;
    const float* in = sel == 0 ? i0 : (sel == 1 ? i1 : (sel == 2 ? i2 : i3));
    u16* o = out + (size_t)sel * n8 * 8;
    int i = blockIdx.x * 256 + threadIdx.x;
    const int stride = gridDim.x * 256;
    for (; i < n8; i += stride) {
        const float4* p = (const float4*)(in + (size_t)i * 8);
        float4 a = p[0], b = p[1];
        ushort4 lo, hi;
        lo.x = f2bf(a.x); lo.y = f2bf(a.y); lo.z = f2bf(a.z); lo.w = f2bf(a.w);
        hi.x = f2bf(b.x); hi.y = f2bf(b.y); hi.z = f2bf(b.z); hi.w = f2bf(b.w);
        ((ushort4*)o)[i * 2] = lo;
        ((ushort4*)o)[i * 2 + 1] = hi;
    }
}

// ---------- WKV parallel scan (bf16 k/v/r inputs) ----------
__global__ __launch_bounds__(256) void wkv_part(const float* __restrict__ td,
                                                const u16* __restrict__ k,
                                                const u16* __restrict__ v,
                                                float* __restrict__ Ab,
                                                float* __restrict__ Bb) {
    const int idx = blockIdx.x * 256 + threadIdx.x;     // C*P threads
    const int c = idx & (C_DIM - 1);
    const int p = idx >> 11;
    const float ew = expf(-expf(td[c]));
    float A = 0.f, B = 0.f;
    size_t o = (size_t)(p * WKV_L) * C_DIM + c;
    #pragma unroll 4
    for (int i = 0; i < WKV_L; ++i, o += C_DIM) {
        const float kk = expf(b2f(k[o]));
        A = (A + kk * b2f(v[o])) * ew;
        B = (B + kk) * ew;
    }
    Ab[p * C_DIM + c] = A;
    Bb[p * C_DIM + c] = B;
}

__global__ __launch_bounds__(256) void wkv_comb(const float* __restrict__ td,
                                                const float* __restrict__ st,
                                                const float* __restrict__ Ab,
                                                const float* __restrict__ Bb,
                                                float* __restrict__ Sa,
                                                float* __restrict__ Sb) {
    const int c = blockIdx.x * 256 + threadIdx.x;       // C threads
    const float w = -expf(td[c]);
    const float dL = expf(w * (float)WKV_L);            // ew^L
    float a = st[c];
    float b = st[C_DIM + c];
    #pragma unroll 4
    for (int p = 0; p < WKV_P; ++p) {
        Sa[p * C_DIM + c] = a;
        Sb[p * C_DIM + c] = b;
        a = dL * a + Ab[p * C_DIM + c];
        b = dL * b + Bb[p * C_DIM + c];
    }
}

__global__ __launch_bounds__(256) void wkv_emit(const float* __restrict__ td,
                                                const float* __restrict__ tf,
                                                const u16* __restrict__ k,
                                                const u16* __restrict__ v,
                                                const u16* __restrict__ r,
                                                const float* __restrict__ Sa,
                                                const float* __restrict__ Sb,
                                                u16* __restrict__ pout) {
    const int idx = blockIdx.x * 256 + threadIdx.x;     // C*P threads
    const int c = idx & (C_DIM - 1);
    const int p = idx >> 11;
    const float u = tf[c];
    const float w = -expf(td[c]);
    const float ew = expf(w);
    float a = Sa[p * C_DIM + c];
    float b = Sb[p * C_DIM + c];
    size_t o = (size_t)(p * WKV_L) * C_DIM + c;
    #pragma unroll 2
    for (int i = 0; i < WKV_L; ++i, o += C_DIM) {
        const float kt = b2f(k[o]), vt = b2f(v[o]), rt = b2f(r[o]);
        const float e = expf(u + w + kt);
        const float y = (a + e * vt) / (b + e);
        const float kk = expf(kt);
        a = (a + kk * vt) * ew;
        b = (b + kk) * ew;
        const float sr = 1.f / (1.f + expf(-rt));
        pout[o] = f2bf(sr * y);
    }
}

enum { EPI_F32 = 0, EPI_ADDX = 1, EPI_RELU2 = 2, EPI_SIGMULADD = 3,
       EPI_SIGMULADD4 = 4, EPI_BF16 = 5 };

// ---------- 128x128 bf16 NT GEMM — 3-slot pipeline (R9, proven) ----------
template <int EPI>
__global__ __launch_bounds__(256, 3) void gemm_bt(
        const u16* __restrict__ A, int lda, long a_zs,
        const u16* __restrict__ B, int ldb, long b_zs,
        long koff, int Kloop,
        void* __restrict__ outp, int ldo, long o_zs,
        const float* __restrict__ aux1, const float* __restrict__ aux2) {
    __shared__ u16 lds[3 * 8192];   // 48 KiB: 3 slots x (A 8KB + B 8KB)
    const int tid = threadIdx.x;
    const int l = tid & 63, w = tid >> 6;
    const int wr2 = w >> 1, wc2 = w & 1;     // 2x2 waves of 64x64

    const int gx = gridDim.x, gy = gridDim.y;
    const int nxy = gx * gy;
    const int flat = (blockIdx.z * gy + blockIdx.y) * gx + blockIdx.x;
    const int cpx = (nxy * gridDim.z) >> 3;
    const int swz = (flat & 7) * cpx + (flat >> 3);
    const int z = swz / nxy;
    const int rem = swz - z * nxy;
    const int bm = rem % gy;
    const int bn = rem / gy;

    const u16* Ag = A + (size_t)z * a_zs + (size_t)z * koff + (size_t)bm * 128 * lda;
    const u16* Bg = B + (size_t)z * b_zs + (size_t)z * koff + (size_t)bn * 128 * ldb;

    long gA[2], gB[2];
    int dA[2], dB[2];
    #pragma unroll
    for (int j = 0; j < 2; ++j) {
        const int off = j * 4096 + w * 1024 + l * 16;
        const int row = off >> 6;
        const int cb = (off & 63) ^ (((off >> 9) & 1) << 5);
        gA[j] = (long)row * lda + (cb >> 1);
        gB[j] = (long)row * ldb + (cb >> 1);
        dA[j] = j * 2048 + w * 512;
        dB[j] = 4096 + j * 2048 + w * 512;
    }

    int offA[4], offB[4];
    #pragma unroll
    for (int m = 0; m < 4; ++m) {
        const int lin = (wr2 * 64 + m * 16 + (l & 15)) * 64 + ((l >> 4) << 4);
        offA[m] = (lin ^ (((lin >> 9) & 1) << 5)) >> 1;
    }
    #pragma unroll
    for (int n = 0; n < 4; ++n) {
        const int lin = (wc2 * 64 + n * 16 + (l & 15)) * 64 + ((l >> 4) << 4);
        offB[n] = 4096 + ((lin ^ (((lin >> 9) & 1) << 5)) >> 1);
    }

    const f32x4 fz = {0.f, 0.f, 0.f, 0.f};
    f32x4 acc[4][4];
    #pragma unroll
    for (int m = 0; m < 4; ++m)
        #pragma unroll
        for (int n = 0; n < 4; ++n) acc[m][n] = fz;

    const int NT = Kloop >> 5;

    auto stage = [&](int kt, int sp) {
        const long ko = (long)kt << 5;
        const int sb = sp * 8192;
        async16(Ag + gA[0] + ko, &lds[sb + dA[0]]);
        async16(Ag + gA[1] + ko, &lds[sb + dA[1]]);
        async16(Bg + gB[0] + ko, &lds[sb + dB[0]]);
        async16(Bg + gB[1] + ko, &lds[sb + dB[1]]);
    };

    stage(0, 0);
    stage(1, 1);

    int sr = 0;
    for (int t = 0; t < NT; ++t) {
        asm volatile("s_waitcnt vmcnt(4)" ::: "memory");
        __builtin_amdgcn_s_barrier();
        __builtin_amdgcn_sched_barrier(0);
        {
            const int tp = (t + 2 < NT) ? t + 2 : NT - 1;
            const int sp = (sr == 0) ? 2 : sr - 1;
            stage(tp, sp);
        }
        const int sb = sr * 8192;
        bf16x8 af[4], bfv[4];
        #pragma unroll
        for (int m = 0; m < 4; ++m) af[m] = *(const bf16x8*)&lds[sb + offA[m]];
        #pragma unroll
        for (int n = 0; n < 4; ++n) bfv[n] = *(const bf16x8*)&lds[sb + offB[n]];
        __builtin_amdgcn_s_setprio(1);
        #pragma unroll
        for (int m = 0; m < 2; ++m)
            #pragma unroll
            for (int n = 0; n < 4; ++n)
                acc[m][n] = __builtin_amdgcn_mfma_f32_16x16x32_bf16(af[m], bfv[n], acc[m][n], 0, 0, 0);
        __builtin_amdgcn_s_setprio(0);
        __builtin_amdgcn_s_setprio(1);
        #pragma unroll
        for (int m = 2; m < 4; ++m)
            #pragma unroll
            for (int n = 0; n < 4; ++n)
                acc[m][n] = __builtin_amdgcn_mfma_f32_16x16x32_bf16(af[m], bfv[n], acc[m][n], 0, 0, 0);
        __builtin_amdgcn_s_setprio(0);
        sr = (sr == 2) ? 0 : sr + 1;
    }
    asm volatile("s_waitcnt vmcnt(0)" ::: "memory");

    const int r00 = bm * 128 + wr2 * 64 + ((l >> 4) << 2);
    const int c00 = bn * 128 + wc2 * 64 + (l & 15);
    #pragma unroll
    for (int m = 0; m < 4; ++m) {
        #pragma unroll
        for (int n = 0; n < 4; ++n) {
            #pragma unroll
            for (int j = 0; j < 4; ++j) {
                const int rr = r00 + m * 16 + j;
                const int cc = c00 + n * 16;
                const size_t o = (size_t)rr * ldo + cc;
                const float val = acc[m][n][j];
                if constexpr (EPI == EPI_F32) {
                    ((float*)outp)[(size_t)z * o_zs + o] = val;
                } else if constexpr (EPI == EPI_BF16) {
                    ((u16*)outp)[(size_t)z * o_zs + o] = f2bf(val);
                } else if constexpr (EPI == EPI_ADDX) {
                    ((float*)outp)[o] = aux1[o] + val;
                } else if constexpr (EPI == EPI_RELU2) {
                    const float tp2 = fmaxf(val, 0.f);
                    ((u16*)outp)[o] = f2bf(tp2 * tp2);
                } else if constexpr (EPI == EPI_SIGMULADD) {
                    const float sg = 1.f / (1.f + expf(-val));
                    ((float*)outp)[o] = aux1[o] + sg * aux2[o];
                } else {  // EPI_SIGMULADD4: aux2 = 4 split-K partials, fused sum
                    const float kv = aux2[o]
                                   + aux2[o + (size_t)T_DIM * C_DIM]
                                   + aux2[o + 2 * (size_t)T_DIM * C_DIM]
                                   + aux2[o + 3 * (size_t)T_DIM * C_DIM];
                    const float sg = 1.f / (1.f + expf(-val));
                    ((float*)outp)[o] = aux1[o] + sg * kv;
                }
            }
        }
    }
}

// ---------- 256x256 bf16 NT GEMM — 4-buffer deep-prefetch (R14, proven) ----
template <int EPI>
__global__ __launch_bounds__(512, 2) void gemm4s(
        const u16* __restrict__ A, int lda,
        const u16* __restrict__ B, int ldb,
        long koff, int Kloop,
        void* __restrict__ outp, int ldo, long o_zs) {
    __shared__ u16 lds[4 * 16384];   // 128 KiB
    const int tid = threadIdx.x;
    const int l = tid & 63, w = tid >> 6;
    const int wm = w >> 2, wn = w & 3;

    const int gx = gridDim.x, gy = gridDim.y;
    const int nxy = gx * gy;
    const int flat = (blockIdx.z * gy + blockIdx.y) * gx + blockIdx.x;
    const int cpx = (nxy * gridDim.z) >> 3;
    const int swzb = (flat & 7) * cpx + (flat >> 3);
    const int z = swzb / nxy;
    const int rem = swzb - z * nxy;
    const int bm = rem % gy;
    const int bn = rem / gy;

    const u16* Ag = A + (size_t)z * koff + (size_t)bm * 256 * lda;
    const u16* Bg = B + (size_t)z * koff + (size_t)bn * 256 * ldb;

    long srcA[2], srcB[2];
    int dstA[2], dstB[2];
    #pragma unroll
    for (int h = 0; h < 2; ++h) {
        const int off = h * 8192 + w * 1024 + l * 16;   // byte in 16KB region
        const int row = off >> 6;                        // 64B rows
        const int cbyte = (off & 63) ^ (((off >> 9) & 1) << 5);
        srcA[h] = (long)row * lda + (cbyte >> 1);
        srcB[h] = (long)row * ldb + (cbyte >> 1);
        dstA[h] = off >> 1;
        dstB[h] = 8192 + (off >> 1);
    }

    int offAL[4], offAH[4], offB[4];
    #pragma unroll
    for (int mi = 0; mi < 4; ++mi) {
        int row = wm * 128 + mi * 16 + (l & 15);
        int lin = row * 64 + ((l >> 4) << 4);
        offAL[mi] = (lin ^ (((lin >> 9) & 1) << 5)) >> 1;
        lin = (row + 64) * 64 + ((l >> 4) << 4);
        offAH[mi] = (lin ^ (((lin >> 9) & 1) << 5)) >> 1;
    }
    #pragma unroll
    for (int n = 0; n < 4; ++n) {
        const int row = wn * 64 + n * 16 + (l & 15);
        const int lin = row * 64 + ((l >> 4) << 4);
        offB[n] = 8192 + ((lin ^ (((lin >> 9) & 1) << 5)) >> 1);
    }

    const f32x4 fz = {0.f, 0.f, 0.f, 0.f};
    f32x4 acc[8][4];
    #pragma unroll
    for (int m = 0; m < 8; ++m)
        #pragma unroll
        for (int n = 0; n < 4; ++n) acc[m][n] = fz;

    const int NT = Kloop >> 5;          // K-tiles of 32 (>=4, even at all sites)

    auto stgA = [&](int kt, int buf, int h) {
        async16(Ag + srcA[h] + (long)kt * 32, &lds[buf * 16384 + dstA[h]]);
    };
    auto stgB = [&](int kt, int buf, int h) {
        async16(Bg + srcB[h] + (long)kt * 32, &lds[buf * 16384 + dstB[h]]);
    };

    // prologue: tiles 0,1,2 staged (12 loads); vmcnt(8) -> tile 0 landed
    stgA(0, 0, 0); stgA(0, 0, 1); stgB(0, 0, 0); stgB(0, 0, 1);
    stgA(1, 1, 0); stgA(1, 1, 1); stgB(1, 1, 0); stgB(1, 1, 1);
    stgA(2, 2, 0); stgA(2, 2, 1); stgB(2, 2, 0); stgB(2, 2, 1);
    asm volatile("s_waitcnt vmcnt(8)" ::: "memory");
    __builtin_amdgcn_s_barrier();

    bf16x8 aX[4], bX[4], aY[4], bY[4];
    #pragma unroll
    for (int mi = 0; mi < 4; ++mi) aX[mi] = *(const bf16x8*)&lds[offAL[mi]];
    #pragma unroll
    for (int n = 0; n < 4; ++n) bX[n] = *(const bf16x8*)&lds[offB[n]];

    auto tile = [&](int kt, bf16x8 (&aC)[4], bf16x8 (&bbC)[4],
                    bf16x8 (&aN)[4], bf16x8 (&bbN)[4]) {
        const int cb = (kt & 3) * 16384;
        const int nb = ((kt + 1) & 3) * 16384;
        const int tb = (kt + 3) & 3;
        const int ksrc = (kt + 3 < NT) ? kt + 3 : NT - 1;
        bf16x8 aH[4];
        // ---- ph0: read m4-7 (cur buf) | stage A halves of kt+3 ----
        #pragma unroll
        for (int mi = 0; mi < 4; ++mi) aH[mi] = *(const bf16x8*)&lds[cb + offAH[mi]];
        stgA(ksrc, tb, 0); stgA(ksrc, tb, 1);
        __builtin_amdgcn_s_barrier();
        asm volatile("s_waitcnt lgkmcnt(4)" ::: "memory");   // prev-phase reads done
        __builtin_amdgcn_sched_barrier(0);
        __builtin_amdgcn_s_setprio(1);
        #pragma unroll
        for (int mi = 0; mi < 4; ++mi)
            #pragma unroll
            for (int n = 0; n < 4; ++n)
                acc[mi][n] = __builtin_amdgcn_mfma_f32_16x16x32_bf16(aC[mi], bbC[n], acc[mi][n], 0, 0, 0);
        __builtin_amdgcn_s_setprio(0);
        // deep-prefetch checkpoint: newest 6 loads {A(kt+3),B(kt+2),A(kt+2)}
        // may remain; tile kt+1 fully landed. Barrier orders cross-wave.
        asm volatile("s_waitcnt vmcnt(6)" ::: "memory");
        __builtin_amdgcn_s_barrier();
        // ---- ph1: read next tile m0-3+B (next buf) | stage B halves of kt+3 --
        #pragma unroll
        for (int mi = 0; mi < 4; ++mi) aN[mi] = *(const bf16x8*)&lds[nb + offAL[mi]];
        #pragma unroll
        for (int n = 0; n < 4; ++n) bbN[n] = *(const bf16x8*)&lds[nb + offB[n]];
        stgB(ksrc, tb, 0); stgB(ksrc, tb, 1);
        __builtin_amdgcn_s_barrier();
        asm volatile("s_waitcnt lgkmcnt(8)" ::: "memory");   // ph0's aH done
        __builtin_amdgcn_sched_barrier(0);
        __builtin_amdgcn_s_setprio(1);
        #pragma unroll
        for (int mi = 0; mi < 4; ++mi)
            #pragma unroll
            for (int n = 0; n < 4; ++n)
                acc[4 + mi][n] = __builtin_amdgcn_mfma_f32_16x16x32_bf16(aH[mi], bbC[n], acc[4 + mi][n], 0, 0, 0);
        __builtin_amdgcn_s_setprio(0);
        __builtin_amdgcn_s_barrier();
    };

    for (int kt = 0; kt < NT; kt += 2) {
        tile(kt, aX, bX, aY, bY);
        tile(kt + 1, aY, bY, aX, bX);
    }
    asm volatile("s_waitcnt vmcnt(0)" ::: "memory");  // drain tail stages

    // --- epilogue (verified 256²/8-wave mapping) ---
    const int r00 = bm * 256 + wm * 128 + ((l >> 4) << 2);
    const int c00 = bn * 256 + wn * 64 + (l & 15);
    #pragma unroll
    for (int m = 0; m < 8; ++m) {
        #pragma unroll
        for (int n = 0; n < 4; ++n) {
            #pragma unroll
            for (int j = 0; j < 4; ++j) {
                const int rr = r00 + m * 16 + j;
                const int cc = c00 + n * 16;
                const size_t o = (size_t)rr * ldo + cc;
                const float val = acc[m][n][j];
                if constexpr (EPI == EPI_F32) {
                    ((float*)outp)[(size_t)z * o_zs + o] = val;
                } else {  // EPI_RELU2
                    const float tp2 = fmaxf(val, 0.f);
                    ((u16*)outp)[o] = f2bf(tp2 * tp2);
                }
            }
        }
    }
}

// ---------- launcher ----------
extern "C" void kernel_launch(void* const* d_in, const int* in_sizes, int n_in,
                              void* d_out, int out_size, void* d_ws, size_t ws_size,
                              hipStream_t stream) {
    const float* x         = (const float*)d_in[0];
    const float* att_shift = (const float*)d_in[1];
    const float* wkv_state = (const float*)d_in[2];
    const float* ffn_shift = (const float*)d_in[3];
    const float* ln1w = (const float*)d_in[4];
    const float* ln1b = (const float*)d_in[5];
    const float* ln2w = (const float*)d_in[6];
    const float* ln2b = (const float*)d_in[7];
    const float* tmk  = (const float*)d_in[8];
    const float* tmv  = (const float*)d_in[9];
    const float* tmr  = (const float*)d_in[10];
    const float* td   = (const float*)d_in[11];
    const float* tf   = (const float*)d_in[12];
    const float* Wk   = (const float*)d_in[13];
    const float* Wv   = (const float*)d_in[14];
    const float* Wr   = (const float*)d_in[15];
    const float* Wo   = (const float*)d_in[16];
    const float* ftmk = (const float*)d_in[17];
    const float* ftmr = (const float*)d_in[18];
    const float* Wfk  = (const float*)d_in[19];   // [F, C]
    const float* Wfv  = (const float*)d_in[20];   // [C, F]
    const float* Wfr  = (const float*)d_in[21];   // [C, C]
    float* out = (float*)d_out;

    char* ws = (char*)d_ws;
    const size_t MB = 1ull << 20;
    u16*   xk  = (u16*)(ws + 16 * MB);        // 8 MB bf16       (also fk)
    u16*   xv  = (u16*)(ws + 24 * MB);        // 8 MB bf16       (also fr)
    u16*   xr  = (u16*)(ws + 32 * MB);        // 8 MB bf16
    u16*   kvr = (u16*)(ws + 40 * MB);        // 24 MB bf16: k|v|r [3][T*C]
    u16*   pb  = (u16*)(ws + 88 * MB);        // 8 MB bf16
    float* x1  = (float*)(ws + 96 * MB);      // 16 MB f32
    u16*   kf  = (u16*)(ws + 112 * MB);       // 32 MB bf16 [T,F]
    u16*   Wb  = (u16*)(ws + 144 * MB);       // 32 MB bf16 weight scratch
    // wkv scratch overlays kf region (dead during TimeMix):
    float* wAb = (float*)(ws + 112 * MB);
    float* wBb = (float*)(ws + 112 * MB + 512 * 1024);
    float* wSa = (float*)(ws + 113 * MB);
    float* wSb = (float*)(ws + 113 * MB + 512 * 1024);
    // ffn_value split-K partials: 4 x 16 MB in [32,96) (xr/kvr/pb dead);
    // consumed directly by the recept GEMM's EPI_SIGMULADD4 epilogue.
    float* fvp = (float*)(ws + 32 * MB);

    const int T = T_DIM, C = C_DIM, F = F_DIM;
    const dim3 blk(256), blk5(512);

    // --- TimeMix ---
    ln_mix3<<<T, blk, 0, stream>>>(x, att_shift, ln1w, ln1b, tmk, tmv, tmr, xk, xv, xr);

    // all four CxC weights in one launch: Wb = [Wk|Wv|Wr|Wo]
    cvt4_bf16<<<dim3(1024, 4), blk, 0, stream>>>(Wk, Wv, Wr, Wo, Wb, C * C / 8);
    // batched qkv -> bf16 k|v|r: grid 16x16x3 = 768 blocks (128² kernel)
    gemm_bt<EPI_BF16><<<dim3(C / 128, T / 128, 3), blk, 0, stream>>>(
        xk, C, (long)T * C, Wb, C, (long)C * C, 0, C,
        kvr, C, (long)T * C, nullptr, nullptr);

    wkv_part<<<(C * WKV_P) / 256, blk, 0, stream>>>(
        td, kvr, kvr + (size_t)T * C, wAb, wBb);
    wkv_comb<<<C / 256, blk, 0, stream>>>(td, wkv_state, wAb, wBb, wSa, wSb);
    wkv_emit<<<(C * WKV_P) / 256, blk, 0, stream>>>(
        td, tf, kvr, kvr + (size_t)T * C, kvr + 2 * (size_t)T * C, wSa, wSb, pb);

    // att_out fused +x: 256 blocks (Wo already converted at Wb+3*C*C)
    gemm_bt<EPI_ADDX><<<dim3(C / 128, T / 128, 1), blk, 0, stream>>>(
        pb, C, 0, Wb + 3 * (size_t)C * C, C, 0, 0, C, x1, C, 0, x, nullptr);

    // --- ChannelMix ---
    ln_mix2<<<T, blk, 0, stream>>>(x1, ffn_shift, ln2w, ln2b, ftmk, ftmr, xk, xv);

    cvt_bf16<<<2048, blk, 0, stream>>>(Wfk, Wb, F * C / 8);
    // ffn_key on 256² deep-prefetch kernel: grid 32x8 = 256 blocks
    gemm4s<EPI_RELU2><<<dim3(F / 256, T / 256, 1), blk5, 0, stream>>>(
        xk, C, Wb, C, 0, C, kf, F, 0);

    cvt_bf16<<<2048, blk, 0, stream>>>(Wfv, Wb, C * F / 8);
    // ffn_value on 256², split-K x4 (koff=2048): 256 blocks -> 4 partials
    gemm4s<EPI_F32><<<dim3(C / 256, T / 256, 4), blk5, 0, stream>>>(
        kf, F, Wb, F, 2048, 2048, fvp, C, (long)T * C);

    cvt_bf16<<<2048, blk, 0, stream>>>(Wfr, Wb, C * C / 8);
    // ffn_recept fused: sigmoid(gemm) * (sum of 4 partials) + x1
    gemm_bt<EPI_SIGMULADD4><<<dim3(C / 128, T / 128, 1), blk, 0, stream>>>(
        xv, C, 0, Wb, C, 0, 0, C, out, C, 0, x1, fvp);
}

// Round 17
// 365.138 us; speedup vs baseline: 1.0852x; 1.0365x over previous
//
#include <hip/hip_runtime.h>
#include <hip/hip_bf16.h>

typedef unsigned short u16;
typedef short bf16x8 __attribute__((ext_vector_type(8)));
typedef float f32x4 __attribute__((ext_vector_type(4)));

#define T_DIM 2048
#define C_DIM 2048
#define F_DIM 8192
#define WKV_L 32
#define WKV_P (T_DIM / WKV_L)   // 64 chunks

// ---------- helpers ----------
__device__ __forceinline__ u16 f2bf(float f) {
    unsigned int u = __float_as_uint(f);
    u += 0x7fff + ((u >> 16) & 1);          // round-to-nearest-even
    return (u16)(u >> 16);
}

__device__ __forceinline__ float b2f(u16 v) {
    return __uint_as_float((unsigned int)v << 16);
}

__device__ __forceinline__ void async16(const void* g, void* l) {
    __builtin_amdgcn_global_load_lds(
        (__attribute__((address_space(1))) const unsigned int*)g,
        (__attribute__((address_space(3))) unsigned int*)l, 16, 0, 0);
}

// ---------- fused LayerNorm + token-shift mix (3 outputs) ----------
__global__ __launch_bounds__(256) void ln_mix3(
        const float* __restrict__ x, const float* __restrict__ sh,
        const float* __restrict__ w, const float* __restrict__ b,
        const float* __restrict__ mk, const float* __restrict__ mv,
        const float* __restrict__ mr,
        u16* __restrict__ xk, u16* __restrict__ xv, u16* __restrict__ xr) {
    __shared__ float red[16];
    const int t = blockIdx.x, tid = threadIdx.x;
    const float4* cr = (const float4*)(x + (size_t)t * C_DIM);
    float4 c0 = cr[tid * 2], c1 = cr[tid * 2 + 1];
    float s = c0.x + c0.y + c0.z + c0.w + c1.x + c1.y + c1.z + c1.w;
    float q = c0.x * c0.x + c0.y * c0.y + c0.z * c0.z + c0.w * c0.w
            + c1.x * c1.x + c1.y * c1.y + c1.z * c1.z + c1.w * c1.w;
    float4 p0, p1;
    float sp = 0.f, qp = 0.f;
    if (t > 0) {
        const float4* pr = (const float4*)(x + (size_t)(t - 1) * C_DIM);
        p0 = pr[tid * 2]; p1 = pr[tid * 2 + 1];
        sp = p0.x + p0.y + p0.z + p0.w + p1.x + p1.y + p1.z + p1.w;
        qp = p0.x * p0.x + p0.y * p0.y + p0.z * p0.z + p0.w * p0.w
           + p1.x * p1.x + p1.y * p1.y + p1.z * p1.z + p1.w * p1.w;
    } else {
        const float4* pr = (const float4*)sh;
        p0 = pr[tid * 2]; p1 = pr[tid * 2 + 1];
    }
    #pragma unroll
    for (int off = 32; off > 0; off >>= 1) {
        s += __shfl_down(s, off);   q += __shfl_down(q, off);
        sp += __shfl_down(sp, off); qp += __shfl_down(qp, off);
    }
    const int lane = tid & 63, wv = tid >> 6;
    if (lane == 0) { red[wv] = s; red[4 + wv] = q; red[8 + wv] = sp; red[12 + wv] = qp; }
    __syncthreads();
    if (tid == 0) {
        red[0] += red[1] + red[2] + red[3];
        red[4] += red[5] + red[6] + red[7];
        red[8] += red[9] + red[10] + red[11];
        red[12] += red[13] + red[14] + red[15];
    }
    __syncthreads();
    const float mc = red[0] * (1.f / C_DIM);
    const float ic = rsqrtf(red[4] * (1.f / C_DIM) - mc * mc + 1e-5f);
    const float mp = red[8] * (1.f / C_DIM);
    const float ip = rsqrtf(red[12] * (1.f / C_DIM) - mp * mp + 1e-5f);
    const float4* w4 = (const float4*)w;
    const float4* b4 = (const float4*)b;
    #pragma unroll
    for (int j = 0; j < 2; ++j) {
        const int i4 = tid * 2 + j;
        float4 cv = j ? c1 : c0, pv = j ? p1 : p0;
        float4 wv4 = w4[i4], bv = b4[i4];
        float4 cl, pl;
        cl.x = (cv.x - mc) * ic * wv4.x + bv.x;
        cl.y = (cv.y - mc) * ic * wv4.y + bv.y;
        cl.z = (cv.z - mc) * ic * wv4.z + bv.z;
        cl.w = (cv.w - mc) * ic * wv4.w + bv.w;
        if (t > 0) {
            pl.x = (pv.x - mp) * ip * wv4.x + bv.x;
            pl.y = (pv.y - mp) * ip * wv4.y + bv.y;
            pl.z = (pv.z - mp) * ip * wv4.z + bv.z;
            pl.w = (pv.w - mp) * ip * wv4.w + bv.w;
        } else pl = pv;
        const size_t o = (size_t)t * (C_DIM / 4) + i4;
        float4 m;
        ushort4 r;
        m = ((const float4*)mk)[i4];
        r.x = f2bf(cl.x * m.x + pl.x * (1.f - m.x));
        r.y = f2bf(cl.y * m.y + pl.y * (1.f - m.y));
        r.z = f2bf(cl.z * m.z + pl.z * (1.f - m.z));
        r.w = f2bf(cl.w * m.w + pl.w * (1.f - m.w));
        ((ushort4*)xk)[o] = r;
        m = ((const float4*)mv)[i4];
        r.x = f2bf(cl.x * m.x + pl.x * (1.f - m.x));
        r.y = f2bf(cl.y * m.y + pl.y * (1.f - m.y));
        r.z = f2bf(cl.z * m.z + pl.z * (1.f - m.z));
        r.w = f2bf(cl.w * m.w + pl.w * (1.f - m.w));
        ((ushort4*)xv)[o] = r;
        m = ((const float4*)mr)[i4];
        r.x = f2bf(cl.x * m.x + pl.x * (1.f - m.x));
        r.y = f2bf(cl.y * m.y + pl.y * (1.f - m.y));
        r.z = f2bf(cl.z * m.z + pl.z * (1.f - m.z));
        r.w = f2bf(cl.w * m.w + pl.w * (1.f - m.w));
        ((ushort4*)xr)[o] = r;
    }
}

// ---------- fused LayerNorm + token-shift mix (2 outputs) ----------
__global__ __launch_bounds__(256) void ln_mix2(
        const float* __restrict__ x, const float* __restrict__ sh,
        const float* __restrict__ w, const float* __restrict__ b,
        const float* __restrict__ mk, const float* __restrict__ mr,
        u16* __restrict__ fk, u16* __restrict__ fr) {
    __shared__ float red[16];
    const int t = blockIdx.x, tid = threadIdx.x;
    const float4* cr = (const float4*)(x + (size_t)t * C_DIM);
    float4 c0 = cr[tid * 2], c1 = cr[tid * 2 + 1];
    float s = c0.x + c0.y + c0.z + c0.w + c1.x + c1.y + c1.z + c1.w;
    float q = c0.x * c0.x + c0.y * c0.y + c0.z * c0.z + c0.w * c0.w
            + c1.x * c1.x + c1.y * c1.y + c1.z * c1.z + c1.w * c1.w;
    float4 p0, p1;
    float sp = 0.f, qp = 0.f;
    if (t > 0) {
        const float4* pr = (const float4*)(x + (size_t)(t - 1) * C_DIM);
        p0 = pr[tid * 2]; p1 = pr[tid * 2 + 1];
        sp = p0.x + p0.y + p0.z + p0.w + p1.x + p1.y + p1.z + p1.w;
        qp = p0.x * p0.x + p0.y * p0.y + p0.z * p0.z + p0.w * p0.w
           + p1.x * p1.x + p1.y * p1.y + p1.z * p1.z + p1.w * p1.w;
    } else {
        const float4* pr = (const float4*)sh;
        p0 = pr[tid * 2]; p1 = pr[tid * 2 + 1];
    }
    #pragma unroll
    for (int off = 32; off > 0; off >>= 1) {
        s += __shfl_down(s, off);   q += __shfl_down(q, off);
        sp += __shfl_down(sp, off); qp += __shfl_down(qp, off);
    }
    const int lane = tid & 63, wv = tid >> 6;
    if (lane == 0) { red[wv] = s; red[4 + wv] = q; red[8 + wv] = sp; red[12 + wv] = qp; }
    __syncthreads();
    if (tid == 0) {
        red[0] += red[1] + red[2] + red[3];
        red[4] += red[5] + red[6] + red[7];
        red[8] += red[9] + red[10] + red[11];
        red[12] += red[13] + red[14] + red[15];
    }
    __syncthreads();
    const float mc = red[0] * (1.f / C_DIM);
    const float ic = rsqrtf(red[4] * (1.f / C_DIM) - mc * mc + 1e-5f);
    const float mp = red[8] * (1.f / C_DIM);
    const float ip = rsqrtf(red[12] * (1.f / C_DIM) - mp * mp + 1e-5f);
    const float4* w4 = (const float4*)w;
    const float4* b4 = (const float4*)b;
    #pragma unroll
    for (int j = 0; j < 2; ++j) {
        const int i4 = tid * 2 + j;
        float4 cv = j ? c1 : c0, pv = j ? p1 : p0;
        float4 wv4 = w4[i4], bv = b4[i4];
        float4 cl, pl;
        cl.x = (cv.x - mc) * ic * wv4.x + bv.x;
        cl.y = (cv.y - mc) * ic * wv4.y + bv.y;
        cl.z = (cv.z - mc) * ic * wv4.z + bv.z;
        cl.w = (cv.w - mc) * ic * wv4.w + bv.w;
        if (t > 0) {
            pl.x = (pv.x - mp) * ip * wv4.x + bv.x;
            pl.y = (pv.y - mp) * ip * wv4.y + bv.y;
            pl.z = (pv.z - mp) * ip * wv4.z + bv.z;
            pl.w = (pv.w - mp) * ip * wv4.w + bv.w;
        } else pl = pv;
        const size_t o = (size_t)t * (C_DIM / 4) + i4;
        float4 m;
        ushort4 r;
        m = ((const float4*)mk)[i4];
        r.x = f2bf(cl.x * m.x + pl.x * (1.f - m.x));
        r.y = f2bf(cl.y * m.y + pl.y * (1.f - m.y));
        r.z = f2bf(cl.z * m.z + pl.z * (1.f - m.z));
        r.w = f2bf(cl.w * m.w + pl.w * (1.f - m.w));
        ((ushort4*)fk)[o] = r;
        m = ((const float4*)mr)[i4];
        r.x = f2bf(cl.x * m.x + pl.x * (1.f - m.x));
        r.y = f2bf(cl.y * m.y + pl.y * (1.f - m.y));
        r.z = f2bf(cl.z * m.z + pl.z * (1.f - m.z));
        r.w = f2bf(cl.w * m.w + pl.w * (1.f - m.w));
        ((ushort4*)fr)[o] = r;
    }
}

// four C*C weights in one launch (blockIdx.y selects the array)
__global__ __launch_bounds__(256) void cvt4_bf16(const float* __restrict__ i0,
                                                 const float* __restrict__ i1,
                                                 const float* __restrict__ i2,
                                                 const float* __restrict__ i3,
                                                 u16* __restrict__ out, int n8) {
    const int sel = blockIdx.y;
    const float* in = sel == 0 ? i0 : (sel == 1 ? i1 : (sel == 2 ? i2 : i3));
    u16* o = out + (size_t)sel * n8 * 8;
    int i = blockIdx.x * 256 + threadIdx.x;
    const int stride = gridDim.x * 256;
    for (; i < n8; i += stride) {
        const float4* p = (const float4*)(in + (size_t)i * 8);
        float4 a = p[0], b = p[1];
        ushort4 lo, hi;
        lo.x = f2bf(a.x); lo.y = f2bf(a.y); lo.z = f2bf(a.z); lo.w = f2bf(a.w);
        hi.x = f2bf(b.x); hi.y = f2bf(b.y); hi.z = f2bf(b.z); hi.w = f2bf(b.w);
        ((ushort4*)o)[i * 2] = lo;
        ((ushort4*)o)[i * 2 + 1] = hi;
    }
}

// three ffn weights (different sizes/dsts) in one launch
__global__ __launch_bounds__(256) void cvtF_bf16(
        const float* __restrict__ i0, const float* __restrict__ i1,
        const float* __restrict__ i2,
        u16* __restrict__ o0, u16* __restrict__ o1, u16* __restrict__ o2,
        int n80, int n81, int n82) {
    const int sel = blockIdx.y;
    const float* in = sel == 0 ? i0 : (sel == 1 ? i1 : i2);
    u16* o = sel == 0 ? o0 : (sel == 1 ? o1 : o2);
    const int n8 = sel == 0 ? n80 : (sel == 1 ? n81 : n82);
    int i = blockIdx.x * 256 + threadIdx.x;
    const int stride = gridDim.x * 256;
    for (; i < n8; i += stride) {
        const float4* p = (const float4*)(in + (size_t)i * 8);
        float4 a = p[0], b = p[1];
        ushort4 lo, hi;
        lo.x = f2bf(a.x); lo.y = f2bf(a.y); lo.z = f2bf(a.z); lo.w = f2bf(a.w);
        hi.x = f2bf(b.x); hi.y = f2bf(b.y); hi.z = f2bf(b.z); hi.w = f2bf(b.w);
        ((ushort4*)o)[i * 2] = lo;
        ((ushort4*)o)[i * 2 + 1] = hi;
    }
}

// ---------- WKV parallel scan (bf16 k/v/r inputs) ----------
__global__ __launch_bounds__(256) void wkv_part(const float* __restrict__ td,
                                                const u16* __restrict__ k,
                                                const u16* __restrict__ v,
                                                float* __restrict__ Ab,
                                                float* __restrict__ Bb) {
    const int idx = blockIdx.x * 256 + threadIdx.x;     // C*P threads
    const int c = idx & (C_DIM - 1);
    const int p = idx >> 11;
    const float ew = expf(-expf(td[c]));
    float A = 0.f, B = 0.f;
    size_t o = (size_t)(p * WKV_L) * C_DIM + c;
    #pragma unroll 4
    for (int i = 0; i < WKV_L; ++i, o += C_DIM) {
        const float kk = expf(b2f(k[o]));
        A = (A + kk * b2f(v[o])) * ew;
        B = (B + kk) * ew;
    }
    Ab[p * C_DIM + c] = A;
    Bb[p * C_DIM + c] = B;
}

__global__ __launch_bounds__(256) void wkv_comb(const float* __restrict__ td,
                                                const float* __restrict__ st,
                                                const float* __restrict__ Ab,
                                                const float* __restrict__ Bb,
                                                float* __restrict__ Sa,
                                                float* __restrict__ Sb) {
    const int c = blockIdx.x * 256 + threadIdx.x;       // C threads
    const float w = -expf(td[c]);
    const float dL = expf(w * (float)WKV_L);            // ew^L
    float a = st[c];
    float b = st[C_DIM + c];
    #pragma unroll 4
    for (int p = 0; p < WKV_P; ++p) {
        Sa[p * C_DIM + c] = a;
        Sb[p * C_DIM + c] = b;
        a = dL * a + Ab[p * C_DIM + c];
        b = dL * b + Bb[p * C_DIM + c];
    }
}

__global__ __launch_bounds__(256) void wkv_emit(const float* __restrict__ td,
                                                const float* __restrict__ tf,
                                                const u16* __restrict__ k,
                                                const u16* __restrict__ v,
                                                const u16* __restrict__ r,
                                                const float* __restrict__ Sa,
                                                const float* __restrict__ Sb,
                                                u16* __restrict__ pout) {
    const int idx = blockIdx.x * 256 + threadIdx.x;     // C*P threads
    const int c = idx & (C_DIM - 1);
    const int p = idx >> 11;
    const float u = tf[c];
    const float w = -expf(td[c]);
    const float ew = expf(w);
    float a = Sa[p * C_DIM + c];
    float b = Sb[p * C_DIM + c];
    size_t o = (size_t)(p * WKV_L) * C_DIM + c;
    #pragma unroll 2
    for (int i = 0; i < WKV_L; ++i, o += C_DIM) {
        const float kt = b2f(k[o]), vt = b2f(v[o]), rt = b2f(r[o]);
        const float e = expf(u + w + kt);
        const float y = (a + e * vt) / (b + e);
        const float kk = expf(kt);
        a = (a + kk * vt) * ew;
        b = (b + kk) * ew;
        const float sr = 1.f / (1.f + expf(-rt));
        pout[o] = f2bf(sr * y);
    }
}

enum { EPI_F32 = 0, EPI_ADDX = 1, EPI_RELU2 = 2, EPI_SIGMULADD = 3,
       EPI_SIGMULADD4 = 4, EPI_BF16 = 5 };

// ---------- 128x128 bf16 NT GEMM — 3-slot pipeline (R9, proven) ----------
template <int EPI>
__global__ __launch_bounds__(256, 3) void gemm_bt(
        const u16* __restrict__ A, int lda, long a_zs,
        const u16* __restrict__ B, int ldb, long b_zs,
        long koff, int Kloop,
        void* __restrict__ outp, int ldo, long o_zs,
        const float* __restrict__ aux1, const float* __restrict__ aux2) {
    __shared__ u16 lds[3 * 8192];   // 48 KiB: 3 slots x (A 8KB + B 8KB)
    const int tid = threadIdx.x;
    const int l = tid & 63, w = tid >> 6;
    const int wr2 = w >> 1, wc2 = w & 1;     // 2x2 waves of 64x64

    const int gx = gridDim.x, gy = gridDim.y;
    const int nxy = gx * gy;
    const int flat = (blockIdx.z * gy + blockIdx.y) * gx + blockIdx.x;
    const int cpx = (nxy * gridDim.z) >> 3;
    const int swz = (flat & 7) * cpx + (flat >> 3);
    const int z = swz / nxy;
    const int rem = swz - z * nxy;
    const int bm = rem % gy;
    const int bn = rem / gy;

    const u16* Ag = A + (size_t)z * a_zs + (size_t)z * koff + (size_t)bm * 128 * lda;
    const u16* Bg = B + (size_t)z * b_zs + (size_t)z * koff + (size_t)bn * 128 * ldb;

    long gA[2], gB[2];
    int dA[2], dB[2];
    #pragma unroll
    for (int j = 0; j < 2; ++j) {
        const int off = j * 4096 + w * 1024 + l * 16;
        const int row = off >> 6;
        const int cb = (off & 63) ^ (((off >> 9) & 1) << 5);
        gA[j] = (long)row * lda + (cb >> 1);
        gB[j] = (long)row * ldb + (cb >> 1);
        dA[j] = j * 2048 + w * 512;
        dB[j] = 4096 + j * 2048 + w * 512;
    }

    int offA[4], offB[4];
    #pragma unroll
    for (int m = 0; m < 4; ++m) {
        const int lin = (wr2 * 64 + m * 16 + (l & 15)) * 64 + ((l >> 4) << 4);
        offA[m] = (lin ^ (((lin >> 9) & 1) << 5)) >> 1;
    }
    #pragma unroll
    for (int n = 0; n < 4; ++n) {
        const int lin = (wc2 * 64 + n * 16 + (l & 15)) * 64 + ((l >> 4) << 4);
        offB[n] = 4096 + ((lin ^ (((lin >> 9) & 1) << 5)) >> 1);
    }

    const f32x4 fz = {0.f, 0.f, 0.f, 0.f};
    f32x4 acc[4][4];
    #pragma unroll
    for (int m = 0; m < 4; ++m)
        #pragma unroll
        for (int n = 0; n < 4; ++n) acc[m][n] = fz;

    const int NT = Kloop >> 5;

    auto stage = [&](int kt, int sp) {
        const long ko = (long)kt << 5;
        const int sb = sp * 8192;
        async16(Ag + gA[0] + ko, &lds[sb + dA[0]]);
        async16(Ag + gA[1] + ko, &lds[sb + dA[1]]);
        async16(Bg + gB[0] + ko, &lds[sb + dB[0]]);
        async16(Bg + gB[1] + ko, &lds[sb + dB[1]]);
    };

    stage(0, 0);
    stage(1, 1);

    int sr = 0;
    for (int t = 0; t < NT; ++t) {
        asm volatile("s_waitcnt vmcnt(4)" ::: "memory");
        __builtin_amdgcn_s_barrier();
        __builtin_amdgcn_sched_barrier(0);
        {
            const int tp = (t + 2 < NT) ? t + 2 : NT - 1;
            const int sp = (sr == 0) ? 2 : sr - 1;
            stage(tp, sp);
        }
        const int sb = sr * 8192;
        bf16x8 af[4], bfv[4];
        #pragma unroll
        for (int m = 0; m < 4; ++m) af[m] = *(const bf16x8*)&lds[sb + offA[m]];
        #pragma unroll
        for (int n = 0; n < 4; ++n) bfv[n] = *(const bf16x8*)&lds[sb + offB[n]];
        __builtin_amdgcn_s_setprio(1);
        #pragma unroll
        for (int m = 0; m < 2; ++m)
            #pragma unroll
            for (int n = 0; n < 4; ++n)
                acc[m][n] = __builtin_amdgcn_mfma_f32_16x16x32_bf16(af[m], bfv[n], acc[m][n], 0, 0, 0);
        __builtin_amdgcn_s_setprio(0);
        __builtin_amdgcn_s_setprio(1);
        #pragma unroll
        for (int m = 2; m < 4; ++m)
            #pragma unroll
            for (int n = 0; n < 4; ++n)
                acc[m][n] = __builtin_amdgcn_mfma_f32_16x16x32_bf16(af[m], bfv[n], acc[m][n], 0, 0, 0);
        __builtin_amdgcn_s_setprio(0);
        sr = (sr == 2) ? 0 : sr + 1;
    }
    asm volatile("s_waitcnt vmcnt(0)" ::: "memory");

    const int r00 = bm * 128 + wr2 * 64 + ((l >> 4) << 2);
    const int c00 = bn * 128 + wc2 * 64 + (l & 15);
    #pragma unroll
    for (int m = 0; m < 4; ++m) {
        #pragma unroll
        for (int n = 0; n < 4; ++n) {
            #pragma unroll
            for (int j = 0; j < 4; ++j) {
                const int rr = r00 + m * 16 + j;
                const int cc = c00 + n * 16;
                const size_t o = (size_t)rr * ldo + cc;
                const float val = acc[m][n][j];
                if constexpr (EPI == EPI_F32) {
                    ((float*)outp)[(size_t)z * o_zs + o] = val;
                } else if constexpr (EPI == EPI_BF16) {
                    ((u16*)outp)[(size_t)z * o_zs + o] = f2bf(val);
                } else if constexpr (EPI == EPI_ADDX) {
                    ((float*)outp)[o] = aux1[o] + val;
                } else if constexpr (EPI == EPI_RELU2) {
                    const float tp2 = fmaxf(val, 0.f);
                    ((u16*)outp)[o] = f2bf(tp2 * tp2);
                } else if constexpr (EPI == EPI_SIGMULADD) {
                    const float sg = 1.f / (1.f + expf(-val));
                    ((float*)outp)[o] = aux1[o] + sg * aux2[o];
                } else {  // EPI_SIGMULADD4: aux2 = 4 bf16 split-K partials
                    const u16* p2 = (const u16*)aux2;
                    const float kv = b2f(p2[o])
                                   + b2f(p2[o + (size_t)T_DIM * C_DIM])
                                   + b2f(p2[o + 2 * (size_t)T_DIM * C_DIM])
                                   + b2f(p2[o + 3 * (size_t)T_DIM * C_DIM]);
                    const float sg = 1.f / (1.f + expf(-val));
                    ((float*)outp)[o] = aux1[o] + sg * kv;
                }
            }
        }
    }
}

// ---------- 256x256 bf16 NT GEMM — 4-buffer deep-prefetch (R14, proven) ----
template <int EPI>
__global__ __launch_bounds__(512, 2) void gemm4s(
        const u16* __restrict__ A, int lda,
        const u16* __restrict__ B, int ldb,
        long koff, int Kloop,
        void* __restrict__ outp, int ldo, long o_zs) {
    __shared__ u16 lds[4 * 16384];   // 128 KiB
    const int tid = threadIdx.x;
    const int l = tid & 63, w = tid >> 6;
    const int wm = w >> 2, wn = w & 3;

    const int gx = gridDim.x, gy = gridDim.y;
    const int nxy = gx * gy;
    const int flat = (blockIdx.z * gy + blockIdx.y) * gx + blockIdx.x;
    const int cpx = (nxy * gridDim.z) >> 3;
    const int swzb = (flat & 7) * cpx + (flat >> 3);
    const int z = swzb / nxy;
    const int rem = swzb - z * nxy;
    const int bm = rem % gy;
    const int bn = rem / gy;

    const u16* Ag = A + (size_t)z * koff + (size_t)bm * 256 * lda;
    const u16* Bg = B + (size_t)z * koff + (size_t)bn * 256 * ldb;

    long srcA[2], srcB[2];
    int dstA[2], dstB[2];
    #pragma unroll
    for (int h = 0; h < 2; ++h) {
        const int off = h * 8192 + w * 1024 + l * 16;   // byte in 16KB region
        const int row = off >> 6;                        // 64B rows
        const int cbyte = (off & 63) ^ (((off >> 9) & 1) << 5);
        srcA[h] = (long)row * lda + (cbyte >> 1);
        srcB[h] = (long)row * ldb + (cbyte >> 1);
        dstA[h] = off >> 1;
        dstB[h] = 8192 + (off >> 1);
    }

    int offAL[4], offAH[4], offB[4];
    #pragma unroll
    for (int mi = 0; mi < 4; ++mi) {
        int row = wm * 128 + mi * 16 + (l & 15);
        int lin = row * 64 + ((l >> 4) << 4);
        offAL[mi] = (lin ^ (((lin >> 9) & 1) << 5)) >> 1;
        lin = (row + 64) * 64 + ((l >> 4) << 4);
        offAH[mi] = (lin ^ (((lin >> 9) & 1) << 5)) >> 1;
    }
    #pragma unroll
    for (int n = 0; n < 4; ++n) {
        const int row = wn * 64 + n * 16 + (l & 15);
        const int lin = row * 64 + ((l >> 4) << 4);
        offB[n] = 8192 + ((lin ^ (((lin >> 9) & 1) << 5)) >> 1);
    }

    const f32x4 fz = {0.f, 0.f, 0.f, 0.f};
    f32x4 acc[8][4];
    #pragma unroll
    for (int m = 0; m < 8; ++m)
        #pragma unroll
        for (int n = 0; n < 4; ++n) acc[m][n] = fz;

    const int NT = Kloop >> 5;          // K-tiles of 32 (>=4, even at all sites)

    auto stgA = [&](int kt, int buf, int h) {
        async16(Ag + srcA[h] + (long)kt * 32, &lds[buf * 16384 + dstA[h]]);
    };
    auto stgB = [&](int kt, int buf, int h) {
        async16(Bg + srcB[h] + (long)kt * 32, &lds[buf * 16384 + dstB[h]]);
    };

    // prologue: tiles 0,1,2 staged (12 loads); vmcnt(8) -> tile 0 landed
    stgA(0, 0, 0); stgA(0, 0, 1); stgB(0, 0, 0); stgB(0, 0, 1);
    stgA(1, 1, 0); stgA(1, 1, 1); stgB(1, 1, 0); stgB(1, 1, 1);
    stgA(2, 2, 0); stgA(2, 2, 1); stgB(2, 2, 0); stgB(2, 2, 1);
    asm volatile("s_waitcnt vmcnt(8)" ::: "memory");
    __builtin_amdgcn_s_barrier();

    bf16x8 aX[4], bX[4], aY[4], bY[4];
    #pragma unroll
    for (int mi = 0; mi < 4; ++mi) aX[mi] = *(const bf16x8*)&lds[offAL[mi]];
    #pragma unroll
    for (int n = 0; n < 4; ++n) bX[n] = *(const bf16x8*)&lds[offB[n]];

    auto tile = [&](int kt, bf16x8 (&aC)[4], bf16x8 (&bbC)[4],
                    bf16x8 (&aN)[4], bf16x8 (&bbN)[4]) {
        const int cb = (kt & 3) * 16384;
        const int nb = ((kt + 1) & 3) * 16384;
        const int tb = (kt + 3) & 3;
        const int ksrc = (kt + 3 < NT) ? kt + 3 : NT - 1;
        bf16x8 aH[4];
        // ---- ph0: read m4-7 (cur buf) | stage A halves of kt+3 ----
        #pragma unroll
        for (int mi = 0; mi < 4; ++mi) aH[mi] = *(const bf16x8*)&lds[cb + offAH[mi]];
        stgA(ksrc, tb, 0); stgA(ksrc, tb, 1);
        __builtin_amdgcn_s_barrier();
        asm volatile("s_waitcnt lgkmcnt(4)" ::: "memory");   // prev-phase reads done
        __builtin_amdgcn_sched_barrier(0);
        __builtin_amdgcn_s_setprio(1);
        #pragma unroll
        for (int mi = 0; mi < 4; ++mi)
            #pragma unroll
            for (int n = 0; n < 4; ++n)
                acc[mi][n] = __builtin_amdgcn_mfma_f32_16x16x32_bf16(aC[mi], bbC[n], acc[mi][n], 0, 0, 0);
        __builtin_amdgcn_s_setprio(0);
        asm volatile("s_waitcnt vmcnt(6)" ::: "memory");
        __builtin_amdgcn_s_barrier();
        // ---- ph1: read next tile m0-3+B (next buf) | stage B halves of kt+3 --
        #pragma unroll
        for (int mi = 0; mi < 4; ++mi) aN[mi] = *(const bf16x8*)&lds[nb + offAL[mi]];
        #pragma unroll
        for (int n = 0; n < 4; ++n) bbN[n] = *(const bf16x8*)&lds[nb + offB[n]];
        stgB(ksrc, tb, 0); stgB(ksrc, tb, 1);
        __builtin_amdgcn_s_barrier();
        asm volatile("s_waitcnt lgkmcnt(8)" ::: "memory");   // ph0's aH done
        __builtin_amdgcn_sched_barrier(0);
        __builtin_amdgcn_s_setprio(1);
        #pragma unroll
        for (int mi = 0; mi < 4; ++mi)
            #pragma unroll
            for (int n = 0; n < 4; ++n)
                acc[4 + mi][n] = __builtin_amdgcn_mfma_f32_16x16x32_bf16(aH[mi], bbC[n], acc[4 + mi][n], 0, 0, 0);
        __builtin_amdgcn_s_setprio(0);
        __builtin_amdgcn_s_barrier();
    };

    for (int kt = 0; kt < NT; kt += 2) {
        tile(kt, aX, bX, aY, bY);
        tile(kt + 1, aY, bY, aX, bX);
    }
    asm volatile("s_waitcnt vmcnt(0)" ::: "memory");  // drain tail stages

    // --- epilogue (verified 256²/8-wave mapping) ---
    const int r00 = bm * 256 + wm * 128 + ((l >> 4) << 2);
    const int c00 = bn * 256 + wn * 64 + (l & 15);
    #pragma unroll
    for (int m = 0; m < 8; ++m) {
        #pragma unroll
        for (int n = 0; n < 4; ++n) {
            #pragma unroll
            for (int j = 0; j < 4; ++j) {
                const int rr = r00 + m * 16 + j;
                const int cc = c00 + n * 16;
                const size_t o = (size_t)rr * ldo + cc;
                const float val = acc[m][n][j];
                if constexpr (EPI == EPI_F32) {
                    ((float*)outp)[(size_t)z * o_zs + o] = val;
                } else if constexpr (EPI == EPI_BF16) {
                    ((u16*)outp)[(size_t)z * o_zs + o] = f2bf(val);
                } else {  // EPI_RELU2
                    const float tp2 = fmaxf(val, 0.f);
                    ((u16*)outp)[o] = f2bf(tp2 * tp2);
                }
            }
        }
    }
}

// ---------- launcher ----------
extern "C" void kernel_launch(void* const* d_in, const int* in_sizes, int n_in,
                              void* d_out, int out_size, void* d_ws, size_t ws_size,
                              hipStream_t stream) {
    const float* x         = (const float*)d_in[0];
    const float* att_shift = (const float*)d_in[1];
    const float* wkv_state = (const float*)d_in[2];
    const float* ffn_shift = (const float*)d_in[3];
    const float* ln1w = (const float*)d_in[4];
    const float* ln1b = (const float*)d_in[5];
    const float* ln2w = (const float*)d_in[6];
    const float* ln2b = (const float*)d_in[7];
    const float* tmk  = (const float*)d_in[8];
    const float* tmv  = (const float*)d_in[9];
    const float* tmr  = (const float*)d_in[10];
    const float* td   = (const float*)d_in[11];
    const float* tf   = (const float*)d_in[12];
    const float* Wk   = (const float*)d_in[13];
    const float* Wv   = (const float*)d_in[14];
    const float* Wr   = (const float*)d_in[15];
    const float* Wo   = (const float*)d_in[16];
    const float* ftmk = (const float*)d_in[17];
    const float* ftmr = (const float*)d_in[18];
    const float* Wfk  = (const float*)d_in[19];   // [F, C]
    const float* Wfv  = (const float*)d_in[20];   // [C, F]
    const float* Wfr  = (const float*)d_in[21];   // [C, C]
    float* out = (float*)d_out;

    char* ws = (char*)d_ws;
    const size_t MB = 1ull << 20;
    u16*   Wfrb = (u16*)(ws + 0);             // 8 MB bf16 Wfr   [ffn stage]
    u16*   xk  = (u16*)(ws + 16 * MB);        // 8 MB bf16       (also fk)
    u16*   xv  = (u16*)(ws + 24 * MB);        // 8 MB bf16       (also fr)
    u16*   xr  = (u16*)(ws + 32 * MB);        // 8 MB bf16       [TimeMix]
    u16*   Wfvb = (u16*)(ws + 32 * MB);       // 32 MB bf16 Wfv  [ffn stage]
    u16*   kvr = (u16*)(ws + 40 * MB);        // 24 MB bf16: k|v|r [TimeMix]
    u16*   fvp = (u16*)(ws + 64 * MB);        // 32 MB bf16: 4 partials [ffn]
    u16*   pb  = (u16*)(ws + 88 * MB);        // 8 MB bf16       [TimeMix]
    float* x1  = (float*)(ws + 96 * MB);      // 16 MB f32
    u16*   kf  = (u16*)(ws + 112 * MB);       // 32 MB bf16 [T,F]
    u16*   Wb  = (u16*)(ws + 144 * MB);       // 32 MB bf16 weight scratch
    // wkv scratch overlays kf region (dead during TimeMix):
    float* wAb = (float*)(ws + 112 * MB);
    float* wBb = (float*)(ws + 112 * MB + 512 * 1024);
    float* wSa = (float*)(ws + 113 * MB);
    float* wSb = (float*)(ws + 113 * MB + 512 * 1024);

    const int T = T_DIM, C = C_DIM, F = F_DIM;
    const dim3 blk(256), blk5(512);

    // --- TimeMix ---
    ln_mix3<<<T, blk, 0, stream>>>(x, att_shift, ln1w, ln1b, tmk, tmv, tmr, xk, xv, xr);

    // all four CxC weights in one launch: Wb = [Wk|Wv|Wr|Wo]
    cvt4_bf16<<<dim3(1024, 4), blk, 0, stream>>>(Wk, Wv, Wr, Wo, Wb, C * C / 8);
    // batched qkv -> bf16 k|v|r: grid 16x16x3 = 768 blocks (128² kernel)
    gemm_bt<EPI_BF16><<<dim3(C / 128, T / 128, 3), blk, 0, stream>>>(
        xk, C, (long)T * C, Wb, C, (long)C * C, 0, C,
        kvr, C, (long)T * C, nullptr, nullptr);

    wkv_part<<<(C * WKV_P) / 256, blk, 0, stream>>>(
        td, kvr, kvr + (size_t)T * C, wAb, wBb);
    wkv_comb<<<C / 256, blk, 0, stream>>>(td, wkv_state, wAb, wBb, wSa, wSb);
    wkv_emit<<<(C * WKV_P) / 256, blk, 0, stream>>>(
        td, tf, kvr, kvr + (size_t)T * C, kvr + 2 * (size_t)T * C, wSa, wSb, pb);

    // att_out fused +x: 256 blocks (Wo already converted at Wb+3*C*C)
    gemm_bt<EPI_ADDX><<<dim3(C / 128, T / 128, 1), blk, 0, stream>>>(
        pb, C, 0, Wb + 3 * (size_t)C * C, C, 0, 0, C, x1, C, 0, x, nullptr);

    // --- ChannelMix ---
    ln_mix2<<<T, blk, 0, stream>>>(x1, ffn_shift, ln2w, ln2b, ftmk, ftmr, xk, xv);

    // all three ffn weights in one launch: Wfk->Wb, Wfv->Wfvb, Wfr->Wfrb
    cvtF_bf16<<<dim3(2048, 3), blk, 0, stream>>>(
        Wfk, Wfv, Wfr, Wb, Wfvb, Wfrb, F * C / 8, C * F / 8, C * C / 8);

    // ffn_key on 256² deep-prefetch kernel: grid 32x8 = 256 blocks
    gemm4s<EPI_RELU2><<<dim3(F / 256, T / 256, 1), blk5, 0, stream>>>(
        xk, C, Wb, C, 0, C, kf, F, 0);

    // ffn_value on 256², split-K x4 (koff=2048): 256 blocks -> 4 bf16 partials
    gemm4s<EPI_BF16><<<dim3(C / 256, T / 256, 4), blk5, 0, stream>>>(
        kf, F, Wfvb, F, 2048, 2048, fvp, C, (long)T * C);

    // ffn_recept fused: sigmoid(gemm) * (sum of 4 bf16 partials) + x1
    gemm_bt<EPI_SIGMULADD4><<<dim3(C / 128, T / 128, 1), blk, 0, stream>>>(
        xv, C, 0, Wfrb, C, 0, 0, C, out, C, 0, x1, (const float*)fvp);
}